// Round 11
// baseline (561.591 us; speedup 1.0000x reference)
//
#include <hip/hip_runtime.h>
#include <hip/hip_bf16.h>

#define NN 50000
#define NE 800000
#define NG 256
#define DIN 128
#define DH 512
#define DC 256   // conv channels
#define DL 128   // lin2 out
#define NB 49    // scan blocks: ceil(50000/1024)
#define SLW 32   // slice width (channels): 8 slices x 3.2MB, each fits a 4MB XCD L2

// ---------------- workspace layout (bytes) ----------------
#define XBF_OFF   0UL            // 50000*128*2  = 12,800,000
#define H1BF_OFF  12800000UL     // 50000*512*2  -> 64,000,000
#define HWBF_OFF  64000000UL     // 25,600,000 -> 89,600,000   (slice-major [8][NN][32])
#define H2BF_OFF  89600000UL     // 25,600,000 -> 115,200,000  (row-major)
#define H3BF_OFF  115200000UL    // 25,600,000 -> 140,800,000  (row-major)
#define W1T_OFF   140800000UL    // 131,072
#define WC1T_OFF  140931072UL    // 262,144
#define WC2T_OFF  141193216UL    // 131,072 -> 141,324,288
#define CNT_OFF   141324288UL    // 200,000
#define FILL_OFF  141524288UL    // 200,000
#define DHIST_OFF 141724288UL    // 256   (64 bins)
#define DFILL_OFF 141724544UL    // 256   (memset covers CNT..DFILL = 400,512 B)
#define DINV_OFF  141724800UL    // 200,000
#define RP_OFF    141924800UL    // 200,004 -> 142,124,804
#define BSUM_OFF  142124816UL    // 256
#define DBASE_OFF 142125072UL    // 256
#define EW_OFF    142125344UL    // 3,200,000 -> 145,325,344
#define NORD_OFF  145325344UL    // 200,000 -> 145,525,344

using bf16x8 = __attribute__((ext_vector_type(8))) short;
using f32x4  = __attribute__((ext_vector_type(4))) float;

__device__ __forceinline__ short f2bf(float f) {
  unsigned u = __builtin_bit_cast(unsigned, f);
  unsigned r = u + 0x7fffu + ((u >> 16) & 1u);   // round-to-nearest-even
  return (short)(r >> 16);
}
__device__ __forceinline__ float bf2f(unsigned short u) {
  return __builtin_bit_cast(float, (unsigned)u << 16);
}

// async global->LDS, 16B per lane. LDS dest = wave-uniform base + lane*16.
__device__ __forceinline__ void gload_lds16(const void* g, void* l) {
  typedef const __attribute__((address_space(1))) unsigned gu32;
  typedef __attribute__((address_space(3))) unsigned lu32;
  __builtin_amdgcn_global_load_lds((gu32*)g, (lu32*)l, 16, 0, 0);
}

// ---------------- graph-structure kernels ----------------
__global__ void count_in(const int* __restrict__ dst, int* __restrict__ cnt) {
  int e = blockIdx.x * blockDim.x + threadIdx.x;
  if (e < NE) atomicAdd(&cnt[dst[e]], 1);
}

// ---- scan p1: exclusive scan of cnt -> rowptr; dinv; LDS degree histogram ----
__global__ __launch_bounds__(1024) void scan_p1(const int* __restrict__ cnt,
                                                int* __restrict__ rowptr,
                                                int* __restrict__ bsum,
                                                float* __restrict__ dinv,
                                                int* __restrict__ dhist) {
  __shared__ int wsum[16];
  __shared__ int lhist[64];
  const int idx = blockIdx.x * 1024 + threadIdx.x;
  const int lane = threadIdx.x & 63, wid = threadIdx.x >> 6;
  if (threadIdx.x < 64) lhist[threadIdx.x] = 0;
  int v = (idx < NN) ? cnt[idx] : 0;
  int incl = v;
  #pragma unroll
  for (int s = 1; s < 64; s <<= 1) {
    int t = __shfl_up(incl, s, 64);
    if (lane >= s) incl += t;
  }
  if (lane == 63) wsum[wid] = incl;
  __syncthreads();
  if (wid == 0 && lane < 16) {
    int w = wsum[lane];
    int wincl = w;
    #pragma unroll
    for (int s = 1; s < 16; s <<= 1) {
      int t = __shfl_up(wincl, s, 64);
      if (lane >= s) wincl += t;
    }
    wsum[lane] = wincl - w;
    if (lane == 15) bsum[blockIdx.x] = wincl;
  }
  __syncthreads();
  if (idx < NN) {
    rowptr[idx] = wsum[wid] + incl - v;
    dinv[idx] = 1.0f / sqrtf((float)(v + 1));   // +1 self-loop
    atomicAdd(&lhist[min(v, 63)], 1);
  }
  __syncthreads();
  if (threadIdx.x < 64 && lhist[threadIdx.x]) atomicAdd(&dhist[threadIdx.x], lhist[threadIdx.x]);
}

__global__ void scan_p2(int* __restrict__ bsum, int* __restrict__ rowptr) {
  const int lane = threadIdx.x;
  int v = (lane < NB) ? bsum[lane] : 0;
  int incl = v;
  #pragma unroll
  for (int s = 1; s < 64; s <<= 1) {
    int t = __shfl_up(incl, s, 64);
    if (lane >= s) incl += t;
  }
  if (lane < NB) bsum[lane] = incl - v;
  if (lane == 63) rowptr[NN] = incl;        // == NE
}

// exclusive scan of the 64-bin degree histogram
__global__ void scan_deg(const int* __restrict__ dhist, int* __restrict__ dbase) {
  const int lane = threadIdx.x;   // 64
  int v = dhist[lane];
  int incl = v;
  #pragma unroll
  for (int s = 1; s < 64; s <<= 1) {
    int t = __shfl_up(incl, s, 64);
    if (lane >= s) incl += t;
  }
  dbase[lane] = incl - v;
}

__global__ __launch_bounds__(1024) void scan_p3(int* __restrict__ rowptr,
                                                const int* __restrict__ bsum) {
  const int idx = blockIdx.x * 1024 + threadIdx.x;
  if (idx < NN && blockIdx.x > 0) rowptr[idx] += bsum[blockIdx.x];
}

// fill CSR: packed 4B edge record = src_idx (u16) | bf16(weight) << 16
__global__ void fill_csr(const int* __restrict__ src, const int* __restrict__ dst,
                         const int* __restrict__ rowptr, int* __restrict__ fill,
                         const float* __restrict__ dinv, unsigned* __restrict__ ewp) {
  int e = blockIdx.x * blockDim.x + threadIdx.x;
  if (e < NE) {
    int d = dst[e];
    int s = src[e];
    int pos = rowptr[d] + atomicAdd(&fill[d], 1);
    float w = dinv[d] * dinv[s];
    ewp[pos] = (unsigned)s | ((unsigned)(unsigned short)f2bf(w) << 16);
  }
}

// counting-sort scatter: nodes in degree order (bin-internal order arbitrary;
// per-node results are independent of processing order)
__global__ void node_sort(const int* __restrict__ cnt, const int* __restrict__ dbase,
                          int* __restrict__ dfill, int* __restrict__ nodeord) {
  int i = blockIdx.x * 256 + threadIdx.x;
  if (i < NN) {
    int b = min(cnt[i], 63);
    int pos = dbase[b] + atomicAdd(&dfill[b], 1);
    nodeord[pos] = i;
  }
}

// ---------------- fused prep: x->bf16 + 3 weight transposes ----------------
__global__ void prep(const float* __restrict__ x, short* __restrict__ xbf,
                     const float* __restrict__ W1, short* __restrict__ W1t,
                     const float* __restrict__ Wc1, short* __restrict__ Wc1t,
                     const float* __restrict__ Wc2, short* __restrict__ Wc2t) {
  int idx = blockIdx.x * 256 + threadIdx.x;
  if (idx < 800000) {
    const float4* p = (const float4*)x + (long)idx * 2;
    float4 a = p[0], b = p[1];
    bf16x8 o;
    o[0] = f2bf(a.x); o[1] = f2bf(a.y); o[2] = f2bf(a.z); o[3] = f2bf(a.w);
    o[4] = f2bf(b.x); o[5] = f2bf(b.y); o[6] = f2bf(b.z); o[7] = f2bf(b.w);
    *(bf16x8*)(xbf + (long)idx * 8) = o;
  } else if (idx < 865536) {
    int j = idx - 800000;             // W1t[512][128]
    int n = j >> 7, k = j & 127;
    W1t[j] = f2bf(W1[k * DH + n]);
  } else if (idx < 996608) {
    int j = idx - 865536;             // Wc1t[256][512]
    int n = j >> 9, k = j & 511;
    Wc1t[j] = f2bf(Wc1[k * DC + n]);
  } else if (idx < 1062144) {
    int j = idx - 996608;             // Wc2t[256][256]
    int n = j >> 8, k = j & 255;
    Wc2t[j] = f2bf(Wc2[k * DC + n]);
  }
}

// ---------------- bf16 MFMA GEMM v4: BK=64, optional slice-major C ------------
// 128x128 tile, 4 waves (2x2), 16x16x32 MFMA, 4x4 fragments/wave.
// C_SLICED: C written [8][NN][32] (slice-major) for the aggregation pass.
template<int DO_RELU, int HAS_BIAS, int C_SLICED>
__global__ __launch_bounds__(256) void gemm_mfma4(
    const short* __restrict__ A,   // [M,K] bf16 row-major
    const short* __restrict__ Bt,  // [N,K] bf16
    const float* __restrict__ bias,
    short* __restrict__ Cout, int M, int K, int N)
{
  __shared__ __align__(16) short As[128][64];
  __shared__ __align__(16) short Bs[128][64];
  const int tid  = threadIdx.x;
  const int lane = tid & 63;
  const int wave = tid >> 6;
  const int wr   = wave >> 1;
  const int wc   = wave & 1;
  const int bm = blockIdx.y * 128;
  const int bn = blockIdx.x * 128;

  const int srow = lane >> 3;        // 0..7 within 8-row chunk
  const int scol = (lane & 7) * 8;   // short col base 0..56

  f32x4 acc[4][4];
  #pragma unroll
  for (int m = 0; m < 4; ++m)
    #pragma unroll
    for (int n = 0; n < 4; ++n)
      acc[m][n] = f32x4{0.f, 0.f, 0.f, 0.f};

  const int fr = lane & 15;
  const int kb = (lane >> 4) * 8;

  for (int k0 = 0; k0 < K; k0 += 64) {
    #pragma unroll
    for (int j = 0; j < 4; ++j) {
      const int r = wave * 32 + j * 8;
      gload_lds16(A  + (long)(bm + r + srow) * K + k0 + scol, &As[r][0]);
      gload_lds16(Bt + (long)(bn + r + srow) * K + k0 + scol, &Bs[r][0]);
    }
    __syncthreads();
    #pragma unroll
    for (int kk = 0; kk < 2; ++kk) {
      bf16x8 af[4], bfr[4];
      #pragma unroll
      for (int m = 0; m < 4; ++m)
        af[m] = *(const bf16x8*)&As[wr * 64 + m * 16 + fr][kk * 32 + kb];
      #pragma unroll
      for (int n = 0; n < 4; ++n)
        bfr[n] = *(const bf16x8*)&Bs[wc * 64 + n * 16 + fr][kk * 32 + kb];
      #pragma unroll
      for (int m = 0; m < 4; ++m)
        #pragma unroll
        for (int n = 0; n < 4; ++n)
          acc[m][n] = __builtin_amdgcn_mfma_f32_16x16x32_bf16(af[m], bfr[n], acc[m][n], 0, 0, 0);
    }
    __syncthreads();
  }

  const int cr4 = (lane >> 4) * 4;
  const int cc  = lane & 15;
  #pragma unroll
  for (int m = 0; m < 4; ++m) {
    #pragma unroll
    for (int r = 0; r < 4; ++r) {
      int gm = bm + wr * 64 + m * 16 + cr4 + r;
      if (gm >= M) continue;
      #pragma unroll
      for (int n = 0; n < 4; ++n) {
        int gn = bn + wc * 64 + n * 16 + cc;
        float v = acc[m][n][r];
        if (HAS_BIAS) v += bias[gn];
        if (DO_RELU) v = fmaxf(v, 0.f);
        long cidx = C_SLICED ? ((long)(gn >> 5) * ((long)NN * SLW) + (long)gm * SLW + (gn & 31))
                             : ((long)gm * N + gn);
        Cout[cidx] = f2bf(v);
      }
    }
  }
}

// ---------------- GCN aggregation v8: slice-per-XCD, 8 nodes/wave ----------------
// blockIdx&7 = slice (round-robin block->XCD; v7 measured FETCH 191->27MB).
// 8-lane group owns one node: 4 ch/lane x 8 lanes = its 32-ch slice.
// Nodes processed in degree-sorted order (nodeord) -> uniform group trip counts.
// Instruction count ~= v6 (same gathers/records/VALU per edge), fills ~7x lower.
__global__ __launch_bounds__(256) void aggregate_v8(
    const unsigned short* __restrict__ hw,   // slice-major [8][NN][32]
    const unsigned* __restrict__ ewp,
    const int* __restrict__ rowptr, const float* __restrict__ dinv,
    const int* __restrict__ nodeord, const float* __restrict__ bias,
    unsigned short* __restrict__ out)        // row-major [NN][256]
{
  const int slice = blockIdx.x & 7;
  const int j = (blockIdx.x >> 3) * 32 + (threadIdx.x >> 3);
  const int li = threadIdx.x & 7;
  if (j >= NN) return;
  const int i = nodeord[j];
  const unsigned short* hwS = hw + (long)slice * ((long)NN * SLW) + li * 4;

  float a0 = 0.f, a1 = 0.f, a2 = 0.f, a3 = 0.f;
  const int s0 = rowptr[i], s1 = rowptr[i + 1];
  int e = s0;
  for (; e + 4 <= s1; e += 4) {
    unsigned pk0 = __builtin_nontemporal_load(ewp + e);
    unsigned pk1 = __builtin_nontemporal_load(ewp + e + 1);
    unsigned pk2 = __builtin_nontemporal_load(ewp + e + 2);
    unsigned pk3 = __builtin_nontemporal_load(ewp + e + 3);
    ushort4 v0 = *(const ushort4*)(hwS + (pk0 & 0xffffu) * SLW);
    ushort4 v1 = *(const ushort4*)(hwS + (pk1 & 0xffffu) * SLW);
    ushort4 v2 = *(const ushort4*)(hwS + (pk2 & 0xffffu) * SLW);
    ushort4 v3 = *(const ushort4*)(hwS + (pk3 & 0xffffu) * SLW);
    float w0 = bf2f((unsigned short)(pk0 >> 16));
    float w1 = bf2f((unsigned short)(pk1 >> 16));
    float w2 = bf2f((unsigned short)(pk2 >> 16));
    float w3 = bf2f((unsigned short)(pk3 >> 16));
    a0 += w0 * bf2f(v0.x); a1 += w0 * bf2f(v0.y); a2 += w0 * bf2f(v0.z); a3 += w0 * bf2f(v0.w);
    a0 += w1 * bf2f(v1.x); a1 += w1 * bf2f(v1.y); a2 += w1 * bf2f(v1.z); a3 += w1 * bf2f(v1.w);
    a0 += w2 * bf2f(v2.x); a1 += w2 * bf2f(v2.y); a2 += w2 * bf2f(v2.z); a3 += w2 * bf2f(v2.w);
    a0 += w3 * bf2f(v3.x); a1 += w3 * bf2f(v3.y); a2 += w3 * bf2f(v3.z); a3 += w3 * bf2f(v3.w);
  }
  for (; e < s1; ++e) {
    unsigned pk = __builtin_nontemporal_load(ewp + e);
    float w = bf2f((unsigned short)(pk >> 16));
    ushort4 v = *(const ushort4*)(hwS + (pk & 0xffffu) * SLW);
    a0 += w * bf2f(v.x); a1 += w * bf2f(v.y); a2 += w * bf2f(v.z); a3 += w * bf2f(v.w);
  }
  // self-loop (fp32 weight)
  {
    const float di = dinv[i];
    const float w = di * di;
    ushort4 sv = *(const ushort4*)(hwS + (unsigned)i * SLW);
    a0 += w * bf2f(sv.x); a1 += w * bf2f(sv.y); a2 += w * bf2f(sv.z); a3 += w * bf2f(sv.w);
  }
  const int c = slice * SLW + li * 4;
  const float4 bv = *(const float4*)(bias + c);
  ushort4 o;
  o.x = (unsigned short)f2bf(fmaxf(a0 + bv.x, 0.f));
  o.y = (unsigned short)f2bf(fmaxf(a1 + bv.y, 0.f));
  o.z = (unsigned short)f2bf(fmaxf(a2 + bv.z, 0.f));
  o.w = (unsigned short)f2bf(fmaxf(a3 + bv.w, 0.f));
  // nt-store: don't let scattered write-allocates evict the resident slice
  unsigned long long pk = __builtin_bit_cast(unsigned long long, o);
  __builtin_nontemporal_store(pk, (unsigned long long*)(out + (long)i * DC + c));
}

// ---------------- pool + lin2 + lin3 fused v3 (row-major bf16 input) ----------------
__global__ __launch_bounds__(256) void pool_mlp_v3(
    const unsigned short* __restrict__ h, const int* __restrict__ batch,
    const float* __restrict__ W2, const float* __restrict__ b2,
    const float* __restrict__ W3, const float* __restrict__ b3,
    float* __restrict__ out)
{
  __shared__ float part[4][DC];   // 4 KB
  __shared__ float gmean[DC];
  __shared__ float red[DL];
  const int g = blockIdx.x;
  const int t = threadIdx.x;
  const int wid = t >> 6;
  const int lane = t & 63;
  const int c0 = lane * 4;

  int lo = 0, hi = NN;
  while (lo < hi) { int mid = (lo + hi) >> 1; if (batch[mid] < g) lo = mid + 1; else hi = mid; }
  const int start = lo;
  hi = NN;
  while (lo < hi) { int mid = (lo + hi) >> 1; if (batch[mid] < g + 1) lo = mid + 1; else hi = mid; }
  const int end = lo;

  float4 a0 = {0.f, 0.f, 0.f, 0.f}, a1 = {0.f, 0.f, 0.f, 0.f};
  int i = start + wid;
  for (; i + 4 < end; i += 8) {
    ushort4 v0 = *(const ushort4*)(h + (long)i * DC + c0);
    ushort4 v1 = *(const ushort4*)(h + (long)(i + 4) * DC + c0);
    a0.x += bf2f(v0.x); a0.y += bf2f(v0.y); a0.z += bf2f(v0.z); a0.w += bf2f(v0.w);
    a1.x += bf2f(v1.x); a1.y += bf2f(v1.y); a1.z += bf2f(v1.z); a1.w += bf2f(v1.w);
  }
  if (i < end) {
    ushort4 v0 = *(const ushort4*)(h + (long)i * DC + c0);
    a0.x += bf2f(v0.x); a0.y += bf2f(v0.y); a0.z += bf2f(v0.z); a0.w += bf2f(v0.w);
  }
  a0.x += a1.x; a0.y += a1.y; a0.z += a1.z; a0.w += a1.w;
  *(float4*)&part[wid][c0] = a0;
  __syncthreads();
  if (wid == 0) {
    const float inv = 1.0f / fmaxf((float)(end - start), 1.f);
    float4 s0 = *(const float4*)&part[0][c0];
    float4 s1 = *(const float4*)&part[1][c0];
    float4 s2 = *(const float4*)&part[2][c0];
    float4 s3 = *(const float4*)&part[3][c0];
    float4 m;
    m.x = (s0.x + s1.x + s2.x + s3.x) * inv;
    m.y = (s0.y + s1.y + s2.y + s3.y) * inv;
    m.z = (s0.z + s1.z + s2.z + s3.z) * inv;
    m.w = (s0.w + s1.w + s2.w + s3.w) * inv;
    *(float4*)&gmean[c0] = m;
  }
  __syncthreads();
  if (t < DL) {
    float acc = b2[t];
    for (int k = 0; k < DC; ++k) acc = fmaf(gmean[k], W2[k * DL + t], acc);
    red[t] = fmaxf(acc, 0.f) * W3[t];
  }
  __syncthreads();
  for (int s2 = 64; s2 > 0; s2 >>= 1) {
    if (t < s2) red[t] += red[t + s2];
    __syncthreads();
  }
  if (t == 0) out[g] = red[0] + b3[0];
}

// ---------------- launch ----------------
extern "C" void kernel_launch(void* const* d_in, const int* in_sizes, int n_in,
                              void* d_out, int out_size, void* d_ws, size_t ws_size,
                              hipStream_t stream) {
  const float* x    = (const float*)d_in[0];
  const int*   ei   = (const int*)d_in[1];
  const int*   bat  = (const int*)d_in[2];
  const float* W1   = (const float*)d_in[3];
  const float* b1   = (const float*)d_in[4];
  const float* Wc1  = (const float*)d_in[5];
  const float* bc1  = (const float*)d_in[6];
  const float* Wc2  = (const float*)d_in[7];
  const float* bc2  = (const float*)d_in[8];
  const float* W2   = (const float*)d_in[9];
  const float* b2   = (const float*)d_in[10];
  const float* W3   = (const float*)d_in[11];
  const float* b3   = (const float*)d_in[12];
  float* out = (float*)d_out;

  char* ws = (char*)d_ws;
  short* xbf    = (short*)(ws + XBF_OFF);
  short* h1bf   = (short*)(ws + H1BF_OFF);
  unsigned short* hwbf = (unsigned short*)(ws + HWBF_OFF);
  unsigned short* h2bf = (unsigned short*)(ws + H2BF_OFF);
  unsigned short* h3bf = (unsigned short*)(ws + H3BF_OFF);
  short* W1t    = (short*)(ws + W1T_OFF);
  short* Wc1t   = (short*)(ws + WC1T_OFF);
  short* Wc2t   = (short*)(ws + WC2T_OFF);
  int*   cnt    = (int*)  (ws + CNT_OFF);
  int*   fill   = (int*)  (ws + FILL_OFF);
  int*   dhist  = (int*)  (ws + DHIST_OFF);
  int*   dfill  = (int*)  (ws + DFILL_OFF);
  float* dinv   = (float*)(ws + DINV_OFF);
  int*   rowptr = (int*)  (ws + RP_OFF);
  int*   bsum   = (int*)  (ws + BSUM_OFF);
  int*   dbase  = (int*)  (ws + DBASE_OFF);
  unsigned* ewp = (unsigned*)(ws + EW_OFF);
  int*   nodeord= (int*)  (ws + NORD_OFF);

  const int* srcE = ei;
  const int* dstE = ei + NE;

  // zero cnt + fill + dhist + dfill (contiguous) every call
  hipMemsetAsync(cnt, 0, 2 * NN * sizeof(int) + 512, stream);

  // graph structure
  count_in<<<(NE + 255) / 256, 256, 0, stream>>>(dstE, cnt);
  scan_p1<<<NB, 1024, 0, stream>>>(cnt, rowptr, bsum, dinv, dhist);
  scan_p2<<<1, 64, 0, stream>>>(bsum, rowptr);
  scan_deg<<<1, 64, 0, stream>>>(dhist, dbase);
  scan_p3<<<NB, 1024, 0, stream>>>(rowptr, bsum);
  fill_csr<<<(NE + 255) / 256, 256, 0, stream>>>(srcE, dstE, rowptr, fill, dinv, ewp);
  node_sort<<<(NN + 255) / 256, 256, 0, stream>>>(cnt, dbase, dfill, nodeord);

  // fused conversions (x cvt + 3 weight transposes)
  prep<<<(1062144 + 255) / 256, 256, 0, stream>>>(x, xbf, W1, W1t, Wc1, Wc1t, Wc2, Wc2t);

  // lin1: h1 = relu(x @ W1 + b1) -> bf16 row-major
  {
    dim3 grid(DH / 128, (NN + 127) / 128);
    gemm_mfma4<1, 1, 0><<<grid, 256, 0, stream>>>(xbf, W1t, b1, h1bf, NN, DIN, DH);
  }
  // conv1 matmul: hw = h1 @ Wc1 -> bf16 SLICE-MAJOR
  {
    dim3 grid(DC / 128, (NN + 127) / 128);
    gemm_mfma4<0, 0, 1><<<grid, 256, 0, stream>>>(h1bf, Wc1t, nullptr, (short*)hwbf, NN, DH, DC);
  }
  // conv1 aggregate (slice-per-XCD, degree-sorted) -> h2 row-major
  aggregate_v8<<<8 * ((NN + 31) / 32), 256, 0, stream>>>(hwbf, ewp, rowptr, dinv, nodeord, bc1, h2bf);
  // conv2 matmul: hw = h2 @ Wc2 -> bf16 SLICE-MAJOR
  {
    dim3 grid(DC / 128, (NN + 127) / 128);
    gemm_mfma4<0, 0, 1><<<grid, 256, 0, stream>>>((const short*)h2bf, Wc2t, nullptr, (short*)hwbf, NN, DC, DC);
  }
  // conv2 aggregate -> h3 row-major
  aggregate_v8<<<8 * ((NN + 31) / 32), 256, 0, stream>>>(hwbf, ewp, rowptr, dinv, nodeord, bc2, h3bf);

  // pool + lin2 + lin3
  pool_mlp_v3<<<NG, 256, 0, stream>>>(h3bf, bat, W2, b2, W3, b3, out);
}

// Round 12
// 321.442 us; speedup vs baseline: 1.7471x; 1.7471x over previous
//
#include <hip/hip_runtime.h>
#include <hip/hip_bf16.h>

#define NN 50000
#define NE 800000
#define NG 256
#define DIN 128
#define DH 512
#define DC 256   // conv channels
#define DL 128   // lin2 out
#define NB 49    // scan blocks: ceil(50000/1024)

// ---------------- workspace layout (bytes) ----------------
#define XBF_OFF   0UL            // 50000*128*2  = 12,800,000
#define H1BF_OFF  12800000UL     // 50000*512*2  -> 64,000,000
#define HWBF_OFF  64000000UL     // 25,600,000 -> 89,600,000
#define H2BF_OFF  89600000UL     // 25,600,000 -> 115,200,000
#define H3BF_OFF  115200000UL    // 25,600,000 -> 140,800,000
#define W1T_OFF   140800000UL    // 131,072
#define WC1T_OFF  140931072UL    // 262,144
#define WC2T_OFF  141193216UL    // 131,072 -> 141,324,288
#define CNT_OFF   141324288UL    // 200,000
#define FILL_OFF  141524288UL    // 200,000 (must directly follow CNT: one memset)
#define DINV_OFF  141724288UL    // 200,000
#define RP_OFF    141924288UL    // 200,004
#define BSUM_OFF  142124416UL    // 256
#define EW_OFF    142124800UL    // 3,200,000 -> end 145,324,800

using bf16x8 = __attribute__((ext_vector_type(8))) short;
using f32x4  = __attribute__((ext_vector_type(4))) float;

__device__ __forceinline__ short f2bf(float f) {
  unsigned u = __builtin_bit_cast(unsigned, f);
  unsigned r = u + 0x7fffu + ((u >> 16) & 1u);   // round-to-nearest-even
  return (short)(r >> 16);
}
__device__ __forceinline__ float bf2f(unsigned short u) {
  return __builtin_bit_cast(float, (unsigned)u << 16);
}

// async global->LDS, 16B per lane. LDS dest = wave-uniform base + lane*16.
__device__ __forceinline__ void gload_lds16(const void* g, void* l) {
  typedef const __attribute__((address_space(1))) unsigned gu32;
  typedef __attribute__((address_space(3))) unsigned lu32;
  __builtin_amdgcn_global_load_lds((gu32*)g, (lu32*)l, 16, 0, 0);
}

// ---------------- graph-structure kernels ----------------
__global__ void count_in(const int* __restrict__ dst, int* __restrict__ cnt) {
  int e = blockIdx.x * blockDim.x + threadIdx.x;
  if (e < NE) atomicAdd(&cnt[dst[e]], 1);
}

// ---- scan p1: block-local exclusive scan of cnt -> rowptr; block sums; dinv ----
__global__ __launch_bounds__(1024) void scan_p1(const int* __restrict__ cnt,
                                                int* __restrict__ rowptr,
                                                int* __restrict__ bsum,
                                                float* __restrict__ dinv) {
  __shared__ int wsum[16];
  const int idx = blockIdx.x * 1024 + threadIdx.x;
  const int lane = threadIdx.x & 63, wid = threadIdx.x >> 6;
  int v = (idx < NN) ? cnt[idx] : 0;
  int incl = v;
  #pragma unroll
  for (int s = 1; s < 64; s <<= 1) {
    int t = __shfl_up(incl, s, 64);
    if (lane >= s) incl += t;
  }
  if (lane == 63) wsum[wid] = incl;
  __syncthreads();
  if (wid == 0 && lane < 16) {
    int w = wsum[lane];
    int wincl = w;
    #pragma unroll
    for (int s = 1; s < 16; s <<= 1) {
      int t = __shfl_up(wincl, s, 64);
      if (lane >= s) wincl += t;
    }
    wsum[lane] = wincl - w;                 // exclusive wave offset
    if (lane == 15) bsum[blockIdx.x] = wincl;
  }
  __syncthreads();
  if (idx < NN) {
    rowptr[idx] = wsum[wid] + incl - v;
    dinv[idx] = 1.0f / sqrtf((float)(v + 1));   // +1 self-loop
  }
}

// ---- scan p3 (scan_p2 folded in): each block reduces bsum[0..blockIdx) locally ----
__global__ __launch_bounds__(1024) void scan_p3(int* __restrict__ rowptr,
                                                const int* __restrict__ bsum) {
  __shared__ int off_s;
  const int t = threadIdx.x;
  if (t < 64) {
    int v = (t < NB && t < blockIdx.x) ? bsum[t] : 0;
    #pragma unroll
    for (int s = 32; s > 0; s >>= 1) v += __shfl_down(v, s, 64);
    if (t == 0) off_s = v;
  }
  __syncthreads();
  const int idx = blockIdx.x * 1024 + t;
  if (idx < NN) rowptr[idx] += off_s;
  if (blockIdx.x == 0 && t == 0) rowptr[NN] = NE;   // total is the constant NE
}

// ---------------- fused fill_csr + conversions ----------------
// blocks [0, 3125): edge records (NE = 800000 = 3125*256 exactly).
// packed 4B edge record = src_idx (u16) | bf16(dinv[d]*dinv[s]) << 16.
// blocks >= 3125: x->bf16 cvt (8 elems/thread) then 3 weight transposes.
__global__ void fill_prep(const int* __restrict__ src, const int* __restrict__ dst,
                          const int* __restrict__ rowptr, int* __restrict__ fill,
                          const float* __restrict__ dinv, unsigned* __restrict__ ewp,
                          const float* __restrict__ x, short* __restrict__ xbf,
                          const float* __restrict__ W1, short* __restrict__ W1t,
                          const float* __restrict__ Wc1, short* __restrict__ Wc1t,
                          const float* __restrict__ Wc2, short* __restrict__ Wc2t) {
  int gidx = blockIdx.x * 256 + threadIdx.x;
  if (gidx < NE) {
    int d = dst[gidx];
    int s = src[gidx];
    int pos = rowptr[d] + atomicAdd(&fill[d], 1);
    float w = dinv[d] * dinv[s];
    ewp[pos] = (unsigned)s | ((unsigned)(unsigned short)f2bf(w) << 16);
    return;
  }
  int idx = gidx - NE;
  if (idx < 800000) {
    const float4* p = (const float4*)x + (long)idx * 2;
    float4 a = p[0], b = p[1];
    bf16x8 o;
    o[0] = f2bf(a.x); o[1] = f2bf(a.y); o[2] = f2bf(a.z); o[3] = f2bf(a.w);
    o[4] = f2bf(b.x); o[5] = f2bf(b.y); o[6] = f2bf(b.z); o[7] = f2bf(b.w);
    *(bf16x8*)(xbf + (long)idx * 8) = o;
  } else if (idx < 865536) {
    int j = idx - 800000;             // W1t[512][128]
    int n = j >> 7, k = j & 127;
    W1t[j] = f2bf(W1[k * DH + n]);
  } else if (idx < 996608) {
    int j = idx - 865536;             // Wc1t[256][512]
    int n = j >> 9, k = j & 511;
    Wc1t[j] = f2bf(Wc1[k * DC + n]);
  } else if (idx < 1062144) {
    int j = idx - 996608;             // Wc2t[256][256]
    int n = j >> 8, k = j & 255;
    Wc2t[j] = f2bf(Wc2[k * DC + n]);
  }
}

// ---------------- bf16 MFMA GEMM v4: BK=64 (32 MFMA per barrier-pair) ----------
// 128x128 tile, 4 waves (2x2), 16x16x32 MFMA, 4x4 fragments/wave.
// Linear LDS [128][64] (32KB total) staged via global_load_lds width=16.
template<int DO_RELU, int HAS_BIAS>
__global__ __launch_bounds__(256) void gemm_mfma4(
    const short* __restrict__ A,   // [M,K] bf16
    const short* __restrict__ Bt,  // [N,K] bf16
    const float* __restrict__ bias,
    short* __restrict__ Cout, int M, int K, int N)
{
  __shared__ __align__(16) short As[128][64];
  __shared__ __align__(16) short Bs[128][64];
  const int tid  = threadIdx.x;
  const int lane = tid & 63;
  const int wave = tid >> 6;       // 0..3
  const int wr   = wave >> 1;      // M dir
  const int wc   = wave & 1;       // N dir
  const int bm = blockIdx.y * 128;
  const int bn = blockIdx.x * 128;

  const int srow = lane >> 3;        // 0..7 within 8-row chunk
  const int scol = (lane & 7) * 8;   // short col base 0..56

  f32x4 acc[4][4];
  #pragma unroll
  for (int m = 0; m < 4; ++m)
    #pragma unroll
    for (int n = 0; n < 4; ++n)
      acc[m][n] = f32x4{0.f, 0.f, 0.f, 0.f};

  const int fr = lane & 15;          // fragment row/col
  const int kb = (lane >> 4) * 8;    // fragment k base within 32

  for (int k0 = 0; k0 < K; k0 += 64) {
    #pragma unroll
    for (int j = 0; j < 4; ++j) {
      const int r = wave * 32 + j * 8;   // rows [wave*32, wave*32+32)
      gload_lds16(A  + (long)(bm + r + srow) * K + k0 + scol, &As[r][0]);
      gload_lds16(Bt + (long)(bn + r + srow) * K + k0 + scol, &Bs[r][0]);
    }
    __syncthreads();   // drains vmcnt -> LDS writes visible
    #pragma unroll
    for (int kk = 0; kk < 2; ++kk) {
      bf16x8 af[4], bfr[4];
      #pragma unroll
      for (int m = 0; m < 4; ++m)
        af[m] = *(const bf16x8*)&As[wr * 64 + m * 16 + fr][kk * 32 + kb];
      #pragma unroll
      for (int n = 0; n < 4; ++n)
        bfr[n] = *(const bf16x8*)&Bs[wc * 64 + n * 16 + fr][kk * 32 + kb];
      #pragma unroll
      for (int m = 0; m < 4; ++m)
        #pragma unroll
        for (int n = 0; n < 4; ++n)
          acc[m][n] = __builtin_amdgcn_mfma_f32_16x16x32_bf16(af[m], bfr[n], acc[m][n], 0, 0, 0);
    }
    __syncthreads();
  }

  const int cr4 = (lane >> 4) * 4;
  const int cc  = lane & 15;
  #pragma unroll
  for (int m = 0; m < 4; ++m) {
    #pragma unroll
    for (int r = 0; r < 4; ++r) {
      int gm = bm + wr * 64 + m * 16 + cr4 + r;
      if (gm >= M) continue;
      #pragma unroll
      for (int n = 0; n < 4; ++n) {
        int gn = bn + wc * 64 + n * 16 + cc;
        float v = acc[m][n][r];
        if (HAS_BIAS) v += bias[gn];
        if (DO_RELU) v = fmaxf(v, 0.f);
        Cout[(long)gm * N + gn] = f2bf(v);
      }
    }
  }
}

// ---------------- GCN aggregation v6b (row-major, packed records, nt-stores) ----
// 1 wave per node, 4 channels per lane (ushort4, 8B) -> one full 512B row per
// wave-instruction. Edge loop unrolled 8/4/1; records nt-loaded. Output written
// non-temporally so scattered write-allocates don't evict the gather set in L2.
__global__ __launch_bounds__(256) void aggregate_v6(
    const unsigned short* __restrict__ hw, const unsigned* __restrict__ ewp,
    const int* __restrict__ rowptr, const float* __restrict__ dinv,
    const float* __restrict__ bias, unsigned short* __restrict__ out)
{
  const int wid  = threadIdx.x >> 6;
  const int lane = threadIdx.x & 63;
  const int i = blockIdx.x * 4 + wid;
  if (i >= NN) return;
  const int c0 = lane * 4;
  const float di = dinv[i];

  ushort4 sv = *(const ushort4*)(hw + (long)i * DC + c0);
  const float dii = di * di;
  float acc0 = dii * bf2f(sv.x);
  float acc1 = dii * bf2f(sv.y);
  float acc2 = dii * bf2f(sv.z);
  float acc3 = dii * bf2f(sv.w);

  const int s0 = rowptr[i], s1 = rowptr[i + 1];
  int e = s0;
  for (; e + 8 <= s1; e += 8) {
    unsigned pk[8]; ushort4 vv[8];
    #pragma unroll
    for (int j = 0; j < 8; ++j) pk[j] = __builtin_nontemporal_load(ewp + e + j);
    #pragma unroll
    for (int j = 0; j < 8; ++j)
      vv[j] = *(const ushort4*)(hw + (long)(pk[j] & 0xffffu) * DC + c0);
    #pragma unroll
    for (int j = 0; j < 8; ++j) {
      float w = bf2f((unsigned short)(pk[j] >> 16));
      acc0 += w * bf2f(vv[j].x);
      acc1 += w * bf2f(vv[j].y);
      acc2 += w * bf2f(vv[j].z);
      acc3 += w * bf2f(vv[j].w);
    }
  }
  for (; e + 4 <= s1; e += 4) {
    unsigned pk[4]; ushort4 vv[4];
    #pragma unroll
    for (int j = 0; j < 4; ++j) pk[j] = __builtin_nontemporal_load(ewp + e + j);
    #pragma unroll
    for (int j = 0; j < 4; ++j)
      vv[j] = *(const ushort4*)(hw + (long)(pk[j] & 0xffffu) * DC + c0);
    #pragma unroll
    for (int j = 0; j < 4; ++j) {
      float w = bf2f((unsigned short)(pk[j] >> 16));
      acc0 += w * bf2f(vv[j].x);
      acc1 += w * bf2f(vv[j].y);
      acc2 += w * bf2f(vv[j].z);
      acc3 += w * bf2f(vv[j].w);
    }
  }
  for (; e < s1; ++e) {
    unsigned pk = __builtin_nontemporal_load(ewp + e);
    float w = bf2f((unsigned short)(pk >> 16));
    ushort4 v = *(const ushort4*)(hw + (long)(pk & 0xffffu) * DC + c0);
    acc0 += w * bf2f(v.x);
    acc1 += w * bf2f(v.y);
    acc2 += w * bf2f(v.z);
    acc3 += w * bf2f(v.w);
  }
  const float4 bv = *(const float4*)(bias + c0);
  ushort4 o;
  o.x = (unsigned short)f2bf(fmaxf(acc0 + bv.x, 0.f));
  o.y = (unsigned short)f2bf(fmaxf(acc1 + bv.y, 0.f));
  o.z = (unsigned short)f2bf(fmaxf(acc2 + bv.z, 0.f));
  o.w = (unsigned short)f2bf(fmaxf(acc3 + bv.w, 0.f));
  unsigned long long po = __builtin_bit_cast(unsigned long long, o);
  __builtin_nontemporal_store(po, (unsigned long long*)(out + (long)i * DC + c0));
}

// ---------------- pool + lin2 + lin3 fused v3 (bf16 input) ----------------
__global__ __launch_bounds__(256) void pool_mlp_v3(
    const unsigned short* __restrict__ h, const int* __restrict__ batch,
    const float* __restrict__ W2, const float* __restrict__ b2,
    const float* __restrict__ W3, const float* __restrict__ b3,
    float* __restrict__ out)
{
  __shared__ float part[4][DC];   // 4 KB
  __shared__ float gmean[DC];
  __shared__ float red[DL];
  const int g = blockIdx.x;
  const int t = threadIdx.x;
  const int wid = t >> 6;
  const int lane = t & 63;
  const int c0 = lane * 4;

  int lo = 0, hi = NN;
  while (lo < hi) { int mid = (lo + hi) >> 1; if (batch[mid] < g) lo = mid + 1; else hi = mid; }
  const int start = lo;
  hi = NN;
  while (lo < hi) { int mid = (lo + hi) >> 1; if (batch[mid] < g + 1) lo = mid + 1; else hi = mid; }
  const int end = lo;

  float4 a0 = {0.f, 0.f, 0.f, 0.f}, a1 = {0.f, 0.f, 0.f, 0.f};
  int i = start + wid;
  for (; i + 4 < end; i += 8) {
    ushort4 v0 = *(const ushort4*)(h + (long)i * DC + c0);
    ushort4 v1 = *(const ushort4*)(h + (long)(i + 4) * DC + c0);
    a0.x += bf2f(v0.x); a0.y += bf2f(v0.y); a0.z += bf2f(v0.z); a0.w += bf2f(v0.w);
    a1.x += bf2f(v1.x); a1.y += bf2f(v1.y); a1.z += bf2f(v1.z); a1.w += bf2f(v1.w);
  }
  if (i < end) {
    ushort4 v0 = *(const ushort4*)(h + (long)i * DC + c0);
    a0.x += bf2f(v0.x); a0.y += bf2f(v0.y); a0.z += bf2f(v0.z); a0.w += bf2f(v0.w);
  }
  a0.x += a1.x; a0.y += a1.y; a0.z += a1.z; a0.w += a1.w;
  *(float4*)&part[wid][c0] = a0;
  __syncthreads();
  if (wid == 0) {
    const float inv = 1.0f / fmaxf((float)(end - start), 1.f);
    float4 s0 = *(const float4*)&part[0][c0];
    float4 s1 = *(const float4*)&part[1][c0];
    float4 s2 = *(const float4*)&part[2][c0];
    float4 s3 = *(const float4*)&part[3][c0];
    float4 m;
    m.x = (s0.x + s1.x + s2.x + s3.x) * inv;
    m.y = (s0.y + s1.y + s2.y + s3.y) * inv;
    m.z = (s0.z + s1.z + s2.z + s3.z) * inv;
    m.w = (s0.w + s1.w + s2.w + s3.w) * inv;
    *(float4*)&gmean[c0] = m;
  }
  __syncthreads();
  if (t < DL) {
    float acc = b2[t];
    for (int k = 0; k < DC; ++k) acc = fmaf(gmean[k], W2[k * DL + t], acc);
    red[t] = fmaxf(acc, 0.f) * W3[t];
  }
  __syncthreads();
  for (int s2 = 64; s2 > 0; s2 >>= 1) {
    if (t < s2) red[t] += red[t + s2];
    __syncthreads();
  }
  if (t == 0) out[g] = red[0] + b3[0];
}

// ---------------- launch ----------------
extern "C" void kernel_launch(void* const* d_in, const int* in_sizes, int n_in,
                              void* d_out, int out_size, void* d_ws, size_t ws_size,
                              hipStream_t stream) {
  const float* x    = (const float*)d_in[0];
  const int*   ei   = (const int*)d_in[1];
  const int*   bat  = (const int*)d_in[2];
  const float* W1   = (const float*)d_in[3];
  const float* b1   = (const float*)d_in[4];
  const float* Wc1  = (const float*)d_in[5];
  const float* bc1  = (const float*)d_in[6];
  const float* Wc2  = (const float*)d_in[7];
  const float* bc2  = (const float*)d_in[8];
  const float* W2   = (const float*)d_in[9];
  const float* b2   = (const float*)d_in[10];
  const float* W3   = (const float*)d_in[11];
  const float* b3   = (const float*)d_in[12];
  float* out = (float*)d_out;

  char* ws = (char*)d_ws;
  short* xbf    = (short*)(ws + XBF_OFF);
  short* h1bf   = (short*)(ws + H1BF_OFF);
  unsigned short* hwbf = (unsigned short*)(ws + HWBF_OFF);
  unsigned short* h2bf = (unsigned short*)(ws + H2BF_OFF);
  unsigned short* h3bf = (unsigned short*)(ws + H3BF_OFF);
  short* W1t    = (short*)(ws + W1T_OFF);
  short* Wc1t   = (short*)(ws + WC1T_OFF);
  short* Wc2t   = (short*)(ws + WC2T_OFF);
  int*   cnt    = (int*)  (ws + CNT_OFF);
  int*   fill   = (int*)  (ws + FILL_OFF);
  float* dinv   = (float*)(ws + DINV_OFF);
  int*   rowptr = (int*)  (ws + RP_OFF);
  int*   bsum   = (int*)  (ws + BSUM_OFF);
  unsigned* ewp = (unsigned*)(ws + EW_OFF);

  const int* srcE = ei;
  const int* dstE = ei + NE;

  // zero cnt + fill (adjacent) every call
  hipMemsetAsync(cnt, 0, 2 * NN * sizeof(int), stream);

  // graph structure
  count_in<<<(NE + 255) / 256, 256, 0, stream>>>(dstE, cnt);
  scan_p1<<<NB, 1024, 0, stream>>>(cnt, rowptr, bsum, dinv);
  scan_p3<<<NB, 1024, 0, stream>>>(rowptr, bsum);
  // fused: CSR fill (blocks 0..3124) + x cvt + 3 weight transposes
  fill_prep<<<(NE + 1062144 + 255) / 256, 256, 0, stream>>>(
      srcE, dstE, rowptr, fill, dinv, ewp,
      x, xbf, W1, W1t, Wc1, Wc1t, Wc2, Wc2t);

  // lin1: h1 = relu(x @ W1 + b1) -> bf16
  {
    dim3 grid(DH / 128, (NN + 127) / 128);
    gemm_mfma4<1, 1><<<grid, 256, 0, stream>>>(xbf, W1t, b1, h1bf, NN, DIN, DH);
  }
  // conv1 matmul: hw = h1 @ Wc1 -> bf16
  {
    dim3 grid(DC / 128, (NN + 127) / 128);
    gemm_mfma4<0, 0><<<grid, 256, 0, stream>>>(h1bf, Wc1t, nullptr, (short*)hwbf, NN, DH, DC);
  }
  // conv1 aggregate -> h2 (bias + relu) -> bf16
  aggregate_v6<<<(NN + 3) / 4, 256, 0, stream>>>(hwbf, ewp, rowptr, dinv, bc1, h2bf);
  // conv2 matmul: hw = h2 @ Wc2 -> bf16
  {
    dim3 grid(DC / 128, (NN + 127) / 128);
    gemm_mfma4<0, 0><<<grid, 256, 0, stream>>>((const short*)h2bf, Wc2t, nullptr, (short*)hwbf, NN, DC, DC);
  }
  // conv2 aggregate -> h3 (bias + relu) -> bf16
  aggregate_v6<<<(NN + 3) / 4, 256, 0, stream>>>(hwbf, ewp, rowptr, dinv, bc2, h3bf);

  // pool + lin2 + lin3
  pool_mlp_v3<<<NG, 256, 0, stream>>>(h3bf, bat, W2, b2, W3, b3, out);
}

// Round 13
// 306.173 us; speedup vs baseline: 1.8342x; 1.0499x over previous
//
#include <hip/hip_runtime.h>
#include <hip/hip_bf16.h>

#define NN 50000
#define NE 800000
#define NG 256
#define DIN 128
#define DH 512
#define DC 256   // conv channels
#define DL 128   // lin2 out
#define NSB 196  // scan blocks: ceil(50000/256)

// ---------------- workspace layout (bytes) ----------------
#define XBF_OFF   0UL            // 50000*128*2  = 12,800,000
#define H1BF_OFF  12800000UL     // 50000*512*2  -> 64,000,000
#define HWBF_OFF  64000000UL     // 25,600,000 -> 89,600,000
#define H2BF_OFF  89600000UL     // 25,600,000 -> 115,200,000
#define H3BF_OFF  115200000UL    // 25,600,000 -> 140,800,000
#define W1T_OFF   140800000UL    // 131,072
#define WC1T_OFF  140931072UL    // 262,144
#define WC2T_OFF  141193216UL    // 131,072 -> 141,324,288
#define CNT_OFF   141324288UL    // 200,000
#define FILL_OFF  141524288UL    // 200,000 (must directly follow CNT: one memset)
#define DINV_OFF  141724288UL    // 200,000
#define RP_OFF    141924288UL    // 200,004
#define BSUM_OFF  142124416UL    // 1024 (196 ints)
#define EW_OFF    142125440UL    // 3,200,000 -> end 145,325,440

using bf16x8 = __attribute__((ext_vector_type(8))) short;
using f32x4  = __attribute__((ext_vector_type(4))) float;

__device__ __forceinline__ short f2bf(float f) {
  unsigned u = __builtin_bit_cast(unsigned, f);
  unsigned r = u + 0x7fffu + ((u >> 16) & 1u);   // round-to-nearest-even
  return (short)(r >> 16);
}
__device__ __forceinline__ float bf2f(unsigned short u) {
  return __builtin_bit_cast(float, (unsigned)u << 16);
}

// async global->LDS, 16B per lane. LDS dest = wave-uniform base + lane*16.
__device__ __forceinline__ void gload_lds16(const void* g, void* l) {
  typedef const __attribute__((address_space(1))) unsigned gu32;
  typedef __attribute__((address_space(3))) unsigned lu32;
  __builtin_amdgcn_global_load_lds((gu32*)g, (lu32*)l, 16, 0, 0);
}

// ---------------- prep0: edge count + x->bf16 + 3 weight transposes (fused) ----
__global__ __launch_bounds__(256) void prep0(
    const int* __restrict__ src, const int* __restrict__ dst, int* __restrict__ cnt,
    const float* __restrict__ x, short* __restrict__ xbf,
    const float* __restrict__ W1, short* __restrict__ W1t,
    const float* __restrict__ Wc1, short* __restrict__ Wc1t,
    const float* __restrict__ Wc2, short* __restrict__ Wc2t) {
  long gidx = (long)blockIdx.x * 256 + threadIdx.x;
  if (gidx < NE) {                     // degree count
    atomicAdd(&cnt[dst[gidx]], 1);
    return;
  }
  long idx = gidx - NE;
  if (idx < 800000) {                  // x cvt, 8 elems/thread
    const float4* p = (const float4*)x + idx * 2;
    float4 a = p[0], b = p[1];
    bf16x8 o;
    o[0] = f2bf(a.x); o[1] = f2bf(a.y); o[2] = f2bf(a.z); o[3] = f2bf(a.w);
    o[4] = f2bf(b.x); o[5] = f2bf(b.y); o[6] = f2bf(b.z); o[7] = f2bf(b.w);
    *(bf16x8*)(xbf + idx * 8) = o;
  } else if (idx < 865536) {
    int j = (int)(idx - 800000);       // W1t[512][128]
    int n = j >> 7, k = j & 127;
    W1t[j] = f2bf(W1[k * DH + n]);
  } else if (idx < 996608) {
    int j = (int)(idx - 865536);       // Wc1t[256][512]
    int n = j >> 9, k = j & 511;
    Wc1t[j] = f2bf(Wc1[k * DC + n]);
  } else if (idx < 1062144) {
    int j = (int)(idx - 996608);       // Wc2t[256][256]
    int n = j >> 8, k = j & 255;
    Wc2t[j] = f2bf(Wc2[k * DC + n]);
  }
}

// ---------------- scan rider bodies (256-thread blocks) ----------------
__device__ __forceinline__ void scan_p1_body(
    const int* __restrict__ cnt, int* __restrict__ rowptr,
    int* __restrict__ bsum, float* __restrict__ dinv) {
  __shared__ int wsum[4];
  const int b = blockIdx.x;
  const int idx = b * 256 + threadIdx.x;
  const int lane = threadIdx.x & 63, wid = threadIdx.x >> 6;
  int v = (idx < NN) ? cnt[idx] : 0;
  int incl = v;
  #pragma unroll
  for (int s = 1; s < 64; s <<= 1) {
    int t = __shfl_up(incl, s, 64);
    if (lane >= s) incl += t;
  }
  if (lane == 63) wsum[wid] = incl;
  __syncthreads();
  int woff = 0;
  for (int w = 0; w < wid; ++w) woff += wsum[w];
  if (idx < NN) {
    rowptr[idx] = woff + incl - v;
    dinv[idx] = 1.0f / sqrtf((float)(v + 1));   // +1 self-loop
  }
  if (threadIdx.x == 255) bsum[b] = woff + incl;
}

__device__ __forceinline__ void scan_p3_body(
    int* __restrict__ rowptr, const int* __restrict__ bsum) {
  __shared__ int r4[4];
  const int b = blockIdx.x;
  const int t = threadIdx.x;
  const int lane = t & 63, wid = t >> 6;
  int v = (t < b) ? bsum[t] : 0;      // b <= 195 < 256; bsum has 196 entries
  #pragma unroll
  for (int s = 32; s > 0; s >>= 1) v += __shfl_down(v, s, 64);
  if (lane == 0) r4[wid] = v;
  __syncthreads();
  const int off = r4[0] + r4[1] + r4[2] + r4[3];
  const int idx = b * 256 + t;
  if (idx < NN) rowptr[idx] += off;
  if (b == 0 && t == 0) rowptr[NN] = NE;
}

// ---------------- fill CSR: packed 4B edge record = u16 src | bf16 weight ----
__global__ void fill_csr(const int* __restrict__ src, const int* __restrict__ dst,
                         const int* __restrict__ rowptr, int* __restrict__ fill,
                         const float* __restrict__ dinv, unsigned* __restrict__ ewp) {
  int e = blockIdx.x * blockDim.x + threadIdx.x;
  if (e < NE) {
    int d = dst[e];
    int s = src[e];
    int pos = rowptr[d] + atomicAdd(&fill[d], 1);
    float w = dinv[d] * dinv[s];
    ewp[pos] = (unsigned)s | ((unsigned)(unsigned short)f2bf(w) << 16);
  }
}

// ---------------- bf16 MFMA GEMM body: BK=64, XOR-swizzled LDS (T2/G21) --------
// 128x128 tile, 4 waves (2x2), 16x16x32 MFMA, 4x4 fragments/wave.
// Linear LDS dest for global_load_lds; swizzle applied by permuting the per-lane
// GLOBAL source column (m173 pattern): 16B unit u of row R holds logical unit
// u ^ (R&7). Fragment ds_read XORs its column unit by fr&7 -> uniform bank use.
template<int DO_RELU, int HAS_BIAS>
__device__ __forceinline__ void gemm_body(
    const short* __restrict__ A, const short* __restrict__ Bt,
    const float* __restrict__ bias, short* __restrict__ Cout,
    int M, int K, int N, int bxi, int byi)
{
  __shared__ __align__(16) short As[128][64];
  __shared__ __align__(16) short Bs[128][64];
  const int tid  = threadIdx.x;
  const int lane = tid & 63;
  const int wave = tid >> 6;
  const int wr   = wave >> 1;
  const int wc   = wave & 1;
  const int bm = byi * 128;
  const int bn = bxi * 128;

  const int srow = lane >> 3;                  // 0..7 within 8-row chunk
  const int scol = ((lane & 7) ^ srow) * 8;    // swizzled source col (shorts)

  f32x4 acc[4][4];
  #pragma unroll
  for (int m = 0; m < 4; ++m)
    #pragma unroll
    for (int n = 0; n < 4; ++n)
      acc[m][n] = f32x4{0.f, 0.f, 0.f, 0.f};

  const int fr  = lane & 15;
  const int g4  = lane >> 4;                   // 0..3
  const int frx = fr & 7;

  for (int k0 = 0; k0 < K; k0 += 64) {
    #pragma unroll
    for (int j = 0; j < 4; ++j) {
      const int r = wave * 32 + j * 8;
      gload_lds16(A  + (long)(bm + r + srow) * K + k0 + scol, &As[r][0]);
      gload_lds16(Bt + (long)(bn + r + srow) * K + k0 + scol, &Bs[r][0]);
    }
    __syncthreads();   // drains vmcnt -> LDS writes visible
    #pragma unroll
    for (int kk = 0; kk < 2; ++kk) {
      const int col = ((kk * 4 + g4) ^ frx) * 8;   // swizzled read col (shorts)
      bf16x8 af[4], bfr[4];
      #pragma unroll
      for (int m = 0; m < 4; ++m)
        af[m] = *(const bf16x8*)&As[wr * 64 + m * 16 + fr][col];
      #pragma unroll
      for (int n = 0; n < 4; ++n)
        bfr[n] = *(const bf16x8*)&Bs[wc * 64 + n * 16 + fr][col];
      #pragma unroll
      for (int m = 0; m < 4; ++m)
        #pragma unroll
        for (int n = 0; n < 4; ++n)
          acc[m][n] = __builtin_amdgcn_mfma_f32_16x16x32_bf16(af[m], bfr[n], acc[m][n], 0, 0, 0);
    }
    __syncthreads();
  }

  const int cr4 = (lane >> 4) * 4;
  const int cc  = lane & 15;
  #pragma unroll
  for (int m = 0; m < 4; ++m) {
    #pragma unroll
    for (int r = 0; r < 4; ++r) {
      int gm = bm + wr * 64 + m * 16 + cr4 + r;
      if (gm >= M) continue;
      #pragma unroll
      for (int n = 0; n < 4; ++n) {
        int gn = bn + wc * 64 + n * 16 + cc;
        float v = acc[m][n][r];
        if (HAS_BIAS) v += bias[gn];
        if (DO_RELU) v = fmaxf(v, 0.f);
        Cout[(long)gm * N + gn] = f2bf(v);
      }
    }
  }
}

// lin1 GEMM + scan_p1 riders (blocks [0, NSB))
__global__ __launch_bounds__(256) void gemm_lin1(
    const short* __restrict__ A, const short* __restrict__ Bt,
    const float* __restrict__ bias, short* __restrict__ Cout,
    const int* __restrict__ cnt, int* __restrict__ rowptr,
    int* __restrict__ bsum, float* __restrict__ dinv)
{
  if (blockIdx.x < NSB) { scan_p1_body(cnt, rowptr, bsum, dinv); return; }
  int gb = blockIdx.x - NSB;
  gemm_body<1, 1>(A, Bt, bias, Cout, NN, DIN, DH, gb & 3, gb >> 2);
}

// conv1 GEMM + scan_p3 riders (blocks [0, NSB))
__global__ __launch_bounds__(256) void gemm_conv1(
    const short* __restrict__ A, const short* __restrict__ Bt,
    short* __restrict__ Cout, int* __restrict__ rowptr,
    const int* __restrict__ bsum)
{
  if (blockIdx.x < NSB) { scan_p3_body(rowptr, bsum); return; }
  int gb = blockIdx.x - NSB;
  gemm_body<0, 0>(A, Bt, nullptr, Cout, NN, DH, DC, gb & 1, gb >> 1);
}

// conv2 GEMM (plain)
__global__ __launch_bounds__(256) void gemm_conv2(
    const short* __restrict__ A, const short* __restrict__ Bt,
    short* __restrict__ Cout)
{
  gemm_body<0, 0>(A, Bt, nullptr, Cout, NN, DC, DC, blockIdx.x & 1, blockIdx.x >> 1);
}

// ---------------- GCN aggregation v6b (row-major, packed records, nt-stores) ----
__global__ __launch_bounds__(256) void aggregate_v6(
    const unsigned short* __restrict__ hw, const unsigned* __restrict__ ewp,
    const int* __restrict__ rowptr, const float* __restrict__ dinv,
    const float* __restrict__ bias, unsigned short* __restrict__ out)
{
  const int wid  = threadIdx.x >> 6;
  const int lane = threadIdx.x & 63;
  const int i = blockIdx.x * 4 + wid;
  if (i >= NN) return;
  const int c0 = lane * 4;
  const float di = dinv[i];

  ushort4 sv = *(const ushort4*)(hw + (long)i * DC + c0);
  const float dii = di * di;
  float acc0 = dii * bf2f(sv.x);
  float acc1 = dii * bf2f(sv.y);
  float acc2 = dii * bf2f(sv.z);
  float acc3 = dii * bf2f(sv.w);

  const int s0 = rowptr[i], s1 = rowptr[i + 1];
  int e = s0;
  for (; e + 8 <= s1; e += 8) {
    unsigned pk[8]; ushort4 vv[8];
    #pragma unroll
    for (int j = 0; j < 8; ++j) pk[j] = __builtin_nontemporal_load(ewp + e + j);
    #pragma unroll
    for (int j = 0; j < 8; ++j)
      vv[j] = *(const ushort4*)(hw + (long)(pk[j] & 0xffffu) * DC + c0);
    #pragma unroll
    for (int j = 0; j < 8; ++j) {
      float w = bf2f((unsigned short)(pk[j] >> 16));
      acc0 += w * bf2f(vv[j].x);
      acc1 += w * bf2f(vv[j].y);
      acc2 += w * bf2f(vv[j].z);
      acc3 += w * bf2f(vv[j].w);
    }
  }
  for (; e + 4 <= s1; e += 4) {
    unsigned pk[4]; ushort4 vv[4];
    #pragma unroll
    for (int j = 0; j < 4; ++j) pk[j] = __builtin_nontemporal_load(ewp + e + j);
    #pragma unroll
    for (int j = 0; j < 4; ++j)
      vv[j] = *(const ushort4*)(hw + (long)(pk[j] & 0xffffu) * DC + c0);
    #pragma unroll
    for (int j = 0; j < 4; ++j) {
      float w = bf2f((unsigned short)(pk[j] >> 16));
      acc0 += w * bf2f(vv[j].x);
      acc1 += w * bf2f(vv[j].y);
      acc2 += w * bf2f(vv[j].z);
      acc3 += w * bf2f(vv[j].w);
    }
  }
  for (; e < s1; ++e) {
    unsigned pk = __builtin_nontemporal_load(ewp + e);
    float w = bf2f((unsigned short)(pk >> 16));
    ushort4 v = *(const ushort4*)(hw + (long)(pk & 0xffffu) * DC + c0);
    acc0 += w * bf2f(v.x);
    acc1 += w * bf2f(v.y);
    acc2 += w * bf2f(v.z);
    acc3 += w * bf2f(v.w);
  }
  const float4 bv = *(const float4*)(bias + c0);
  ushort4 o;
  o.x = (unsigned short)f2bf(fmaxf(acc0 + bv.x, 0.f));
  o.y = (unsigned short)f2bf(fmaxf(acc1 + bv.y, 0.f));
  o.z = (unsigned short)f2bf(fmaxf(acc2 + bv.z, 0.f));
  o.w = (unsigned short)f2bf(fmaxf(acc3 + bv.w, 0.f));
  unsigned long long po = __builtin_bit_cast(unsigned long long, o);
  __builtin_nontemporal_store(po, (unsigned long long*)(out + (long)i * DC + c0));
}

// ---------------- pool + lin2 + lin3 fused v3 (bf16 input) ----------------
__global__ __launch_bounds__(256) void pool_mlp_v3(
    const unsigned short* __restrict__ h, const int* __restrict__ batch,
    const float* __restrict__ W2, const float* __restrict__ b2,
    const float* __restrict__ W3, const float* __restrict__ b3,
    float* __restrict__ out)
{
  __shared__ float part[4][DC];   // 4 KB
  __shared__ float gmean[DC];
  __shared__ float red[DL];
  const int g = blockIdx.x;
  const int t = threadIdx.x;
  const int wid = t >> 6;
  const int lane = t & 63;
  const int c0 = lane * 4;

  int lo = 0, hi = NN;
  while (lo < hi) { int mid = (lo + hi) >> 1; if (batch[mid] < g) lo = mid + 1; else hi = mid; }
  const int start = lo;
  hi = NN;
  while (lo < hi) { int mid = (lo + hi) >> 1; if (batch[mid] < g + 1) lo = mid + 1; else hi = mid; }
  const int end = lo;

  float4 a0 = {0.f, 0.f, 0.f, 0.f}, a1 = {0.f, 0.f, 0.f, 0.f};
  int i = start + wid;
  for (; i + 4 < end; i += 8) {
    ushort4 v0 = *(const ushort4*)(h + (long)i * DC + c0);
    ushort4 v1 = *(const ushort4*)(h + (long)(i + 4) * DC + c0);
    a0.x += bf2f(v0.x); a0.y += bf2f(v0.y); a0.z += bf2f(v0.z); a0.w += bf2f(v0.w);
    a1.x += bf2f(v1.x); a1.y += bf2f(v1.y); a1.z += bf2f(v1.z); a1.w += bf2f(v1.w);
  }
  if (i < end) {
    ushort4 v0 = *(const ushort4*)(h + (long)i * DC + c0);
    a0.x += bf2f(v0.x); a0.y += bf2f(v0.y); a0.z += bf2f(v0.z); a0.w += bf2f(v0.w);
  }
  a0.x += a1.x; a0.y += a1.y; a0.z += a1.z; a0.w += a1.w;
  *(float4*)&part[wid][c0] = a0;
  __syncthreads();
  if (wid == 0) {
    const float inv = 1.0f / fmaxf((float)(end - start), 1.f);
    float4 s0 = *(const float4*)&part[0][c0];
    float4 s1 = *(const float4*)&part[1][c0];
    float4 s2 = *(const float4*)&part[2][c0];
    float4 s3 = *(const float4*)&part[3][c0];
    float4 m;
    m.x = (s0.x + s1.x + s2.x + s3.x) * inv;
    m.y = (s0.y + s1.y + s2.y + s3.y) * inv;
    m.z = (s0.z + s1.z + s2.z + s3.z) * inv;
    m.w = (s0.w + s1.w + s2.w + s3.w) * inv;
    *(float4*)&gmean[c0] = m;
  }
  __syncthreads();
  if (t < DL) {
    float acc = b2[t];
    for (int k = 0; k < DC; ++k) acc = fmaf(gmean[k], W2[k * DL + t], acc);
    red[t] = fmaxf(acc, 0.f) * W3[t];
  }
  __syncthreads();
  for (int s2 = 64; s2 > 0; s2 >>= 1) {
    if (t < s2) red[t] += red[t + s2];
    __syncthreads();
  }
  if (t == 0) out[g] = red[0] + b3[0];
}

// ---------------- launch ----------------
extern "C" void kernel_launch(void* const* d_in, const int* in_sizes, int n_in,
                              void* d_out, int out_size, void* d_ws, size_t ws_size,
                              hipStream_t stream) {
  const float* x    = (const float*)d_in[0];
  const int*   ei   = (const int*)d_in[1];
  const int*   bat  = (const int*)d_in[2];
  const float* W1   = (const float*)d_in[3];
  const float* b1   = (const float*)d_in[4];
  const float* Wc1  = (const float*)d_in[5];
  const float* bc1  = (const float*)d_in[6];
  const float* Wc2  = (const float*)d_in[7];
  const float* bc2  = (const float*)d_in[8];
  const float* W2   = (const float*)d_in[9];
  const float* b2   = (const float*)d_in[10];
  const float* W3   = (const float*)d_in[11];
  const float* b3   = (const float*)d_in[12];
  float* out = (float*)d_out;

  char* ws = (char*)d_ws;
  short* xbf    = (short*)(ws + XBF_OFF);
  short* h1bf   = (short*)(ws + H1BF_OFF);
  unsigned short* hwbf = (unsigned short*)(ws + HWBF_OFF);
  unsigned short* h2bf = (unsigned short*)(ws + H2BF_OFF);
  unsigned short* h3bf = (unsigned short*)(ws + H3BF_OFF);
  short* W1t    = (short*)(ws + W1T_OFF);
  short* Wc1t   = (short*)(ws + WC1T_OFF);
  short* Wc2t   = (short*)(ws + WC2T_OFF);
  int*   cnt    = (int*)  (ws + CNT_OFF);
  int*   fill   = (int*)  (ws + FILL_OFF);
  float* dinv   = (float*)(ws + DINV_OFF);
  int*   rowptr = (int*)  (ws + RP_OFF);
  int*   bsum   = (int*)  (ws + BSUM_OFF);
  unsigned* ewp = (unsigned*)(ws + EW_OFF);

  const int* srcE = ei;
  const int* dstE = ei + NE;

  // zero cnt + fill (adjacent) every call
  hipMemsetAsync(cnt, 0, 2 * NN * sizeof(int), stream);

  // prep0: degree count (blocks 0..3124) + x cvt + 3 weight transposes
  prep0<<<(NE + 1062144 + 255) / 256, 256, 0, stream>>>(
      srcE, dstE, cnt, x, xbf, W1, W1t, Wc1, Wc1t, Wc2, Wc2t);

  // lin1 GEMM (+ scan_p1 riders): h1 = relu(x @ W1 + b1) -> bf16
  gemm_lin1<<<NSB + 4 * 391, 256, 0, stream>>>(xbf, W1t, b1, h1bf,
                                               cnt, rowptr, bsum, dinv);
  // conv1 GEMM (+ scan_p3 riders): hw = h1 @ Wc1 -> bf16
  gemm_conv1<<<NSB + 2 * 391, 256, 0, stream>>>(h1bf, Wc1t, (short*)hwbf,
                                                rowptr, bsum);
  // CSR fill (needs completed rowptr)
  fill_csr<<<(NE + 255) / 256, 256, 0, stream>>>(srcE, dstE, rowptr, fill, dinv, ewp);

  // conv1 aggregate -> h2 (bias + relu) -> bf16
  aggregate_v6<<<(NN + 3) / 4, 256, 0, stream>>>(hwbf, ewp, rowptr, dinv, bc1, h2bf);
  // conv2 matmul: hw = h2 @ Wc2 -> bf16
  gemm_conv2<<<2 * 391, 256, 0, stream>>>((const short*)h2bf, Wc2t, (short*)hwbf);
  // conv2 aggregate -> h3 (bias + relu) -> bf16
  aggregate_v6<<<(NN + 3) / 4, 256, 0, stream>>>(hwbf, ewp, rowptr, dinv, bc2, h3bf);

  // pool + lin2 + lin3
  pool_mlp_v3<<<NG, 256, 0, stream>>>(h3bf, bat, W2, b2, W3, b3, out);
}

// Round 14
// 304.184 us; speedup vs baseline: 1.8462x; 1.0065x over previous
//
#include <hip/hip_runtime.h>
#include <hip/hip_bf16.h>

#define NN 50000
#define NE 800000
#define NG 256
#define DIN 128
#define DH 512
#define DC 256   // conv channels
#define DL 128   // lin2 out
#define NSB 196  // scan blocks: ceil(50000/256)

// ---------------- workspace layout (bytes) ----------------
#define XBF_OFF   0UL            // 50000*128*2  = 12,800,000
#define H1BF_OFF  12800000UL     // 50000*512*2  -> 64,000,000
#define HWBF_OFF  64000000UL     // 25,600,000 -> 89,600,000
#define H2BF_OFF  89600000UL     // 25,600,000 -> 115,200,000
#define H3BF_OFF  115200000UL    // 25,600,000 -> 140,800,000
#define W1T_OFF   140800000UL    // 131,072
#define WC1T_OFF  140931072UL    // 262,144
#define WC2T_OFF  141193216UL    // 131,072 -> 141,324,288
#define CNT_OFF   141324288UL    // 200,000
#define FILL_OFF  141524288UL    // 200,000
#define EW_OFF    141724288UL    // 1.2M records * 4B = 4,800,000 -> 146,524,288
                                  // (one memset covers CNT+FILL+EW = 5,200,000 B)
#define DINV_OFF  146524288UL    // 200,000
#define RP_OFF    146724288UL    // 200,004
#define BSUM_OFF  146924544UL    // 1024 (196 ints) -> end ~146.93 MB

using bf16x8 = __attribute__((ext_vector_type(8))) short;
using f32x4  = __attribute__((ext_vector_type(4))) float;

__device__ __forceinline__ short f2bf(float f) {
  unsigned u = __builtin_bit_cast(unsigned, f);
  unsigned r = u + 0x7fffu + ((u >> 16) & 1u);   // round-to-nearest-even
  return (short)(r >> 16);
}
__device__ __forceinline__ float bf2f(unsigned short u) {
  return __builtin_bit_cast(float, (unsigned)u << 16);
}

// async global->LDS, 16B per lane. LDS dest = wave-uniform base + lane*16.
__device__ __forceinline__ void gload_lds16(const void* g, void* l) {
  typedef const __attribute__((address_space(1))) unsigned gu32;
  typedef __attribute__((address_space(3))) unsigned lu32;
  __builtin_amdgcn_global_load_lds((gu32*)g, (lu32*)l, 16, 0, 0);
}

// ---------------- prep0: edge count + x->bf16 + 3 weight transposes (fused) ----
__global__ __launch_bounds__(256) void prep0(
    const int* __restrict__ src, const int* __restrict__ dst, int* __restrict__ cnt,
    const float* __restrict__ x, short* __restrict__ xbf,
    const float* __restrict__ W1, short* __restrict__ W1t,
    const float* __restrict__ Wc1, short* __restrict__ Wc1t,
    const float* __restrict__ Wc2, short* __restrict__ Wc2t) {
  long gidx = (long)blockIdx.x * 256 + threadIdx.x;
  if (gidx < NE) {                     // degree count
    atomicAdd(&cnt[dst[gidx]], 1);
    return;
  }
  long idx = gidx - NE;
  if (idx < 800000) {                  // x cvt, 8 elems/thread
    const float4* p = (const float4*)x + idx * 2;
    float4 a = p[0], b = p[1];
    bf16x8 o;
    o[0] = f2bf(a.x); o[1] = f2bf(a.y); o[2] = f2bf(a.z); o[3] = f2bf(a.w);
    o[4] = f2bf(b.x); o[5] = f2bf(b.y); o[6] = f2bf(b.z); o[7] = f2bf(b.w);
    *(bf16x8*)(xbf + idx * 8) = o;
  } else if (idx < 865536) {
    int j = (int)(idx - 800000);       // W1t[512][128]
    int n = j >> 7, k = j & 127;
    W1t[j] = f2bf(W1[k * DH + n]);
  } else if (idx < 996608) {
    int j = (int)(idx - 865536);       // Wc1t[256][512]
    int n = j >> 9, k = j & 511;
    Wc1t[j] = f2bf(Wc1[k * DC + n]);
  } else if (idx < 1062144) {
    int j = (int)(idx - 996608);       // Wc2t[256][256]
    int n = j >> 8, k = j & 255;
    Wc2t[j] = f2bf(Wc2[k * DC + n]);
  }
}

// ---------------- scan rider bodies (256-thread blocks) ----------------
// Scans PADDED degrees ceil(d/8)*8 so every node's edge range is a multiple of 8
// (padding slots are zero records: src=0, weight=+0.0 -> exact-zero contributions).
__device__ __forceinline__ void scan_p1_body(
    const int* __restrict__ cnt, int* __restrict__ rowptr,
    int* __restrict__ bsum, float* __restrict__ dinv) {
  __shared__ int wsum[4];
  const int b = blockIdx.x;
  const int idx = b * 256 + threadIdx.x;
  const int lane = threadIdx.x & 63, wid = threadIdx.x >> 6;
  int v  = (idx < NN) ? cnt[idx] : 0;
  int vp = (idx < NN) ? ((v + 7) & ~7) : 0;   // padded degree
  int incl = vp;
  #pragma unroll
  for (int s = 1; s < 64; s <<= 1) {
    int t = __shfl_up(incl, s, 64);
    if (lane >= s) incl += t;
  }
  if (lane == 63) wsum[wid] = incl;
  __syncthreads();
  int woff = 0;
  for (int w = 0; w < wid; ++w) woff += wsum[w];
  if (idx <= NN) rowptr[idx] = woff + incl - vp;   // idx==NN -> padded total prefix
  if (idx < NN)  dinv[idx] = 1.0f / sqrtf((float)(v + 1));   // +1 self-loop
  if (threadIdx.x == 255) bsum[b] = woff + incl;
}

__device__ __forceinline__ void scan_p3_body(
    int* __restrict__ rowptr, const int* __restrict__ bsum) {
  __shared__ int r4[4];
  const int b = blockIdx.x;
  const int t = threadIdx.x;
  const int lane = t & 63, wid = t >> 6;
  int v = (t < b) ? bsum[t] : 0;      // b <= 195 < 256; bsum has 196 entries
  #pragma unroll
  for (int s = 32; s > 0; s >>= 1) v += __shfl_down(v, s, 64);
  if (lane == 0) r4[wid] = v;
  __syncthreads();
  const int off = r4[0] + r4[1] + r4[2] + r4[3];
  const int idx = b * 256 + t;
  if (idx <= NN) rowptr[idx] += off;
}

// ---------------- fill CSR: packed 4B edge record = u16 src | bf16 weight ----
// Scatters real edges into the first cnt[d] slots of each padded row; the
// remaining slots stay 0 from the memset (zero-weight records).
__global__ void fill_csr(const int* __restrict__ src, const int* __restrict__ dst,
                         const int* __restrict__ rowptr, int* __restrict__ fill,
                         const float* __restrict__ dinv, unsigned* __restrict__ ewp) {
  int e = blockIdx.x * blockDim.x + threadIdx.x;
  if (e < NE) {
    int d = dst[e];
    int s = src[e];
    int pos = rowptr[d] + atomicAdd(&fill[d], 1);
    float w = dinv[d] * dinv[s];
    ewp[pos] = (unsigned)s | ((unsigned)(unsigned short)f2bf(w) << 16);
  }
}

// ---------------- bf16 MFMA GEMM body: BK=64, XOR-swizzled LDS (T2/G21) --------
template<int DO_RELU, int HAS_BIAS>
__device__ __forceinline__ void gemm_body(
    const short* __restrict__ A, const short* __restrict__ Bt,
    const float* __restrict__ bias, short* __restrict__ Cout,
    int M, int K, int N, int bxi, int byi)
{
  __shared__ __align__(16) short As[128][64];
  __shared__ __align__(16) short Bs[128][64];
  const int tid  = threadIdx.x;
  const int lane = tid & 63;
  const int wave = tid >> 6;
  const int wr   = wave >> 1;
  const int wc   = wave & 1;
  const int bm = byi * 128;
  const int bn = bxi * 128;

  const int srow = lane >> 3;                  // 0..7 within 8-row chunk
  const int scol = ((lane & 7) ^ srow) * 8;    // swizzled source col (shorts)

  f32x4 acc[4][4];
  #pragma unroll
  for (int m = 0; m < 4; ++m)
    #pragma unroll
    for (int n = 0; n < 4; ++n)
      acc[m][n] = f32x4{0.f, 0.f, 0.f, 0.f};

  const int fr  = lane & 15;
  const int g4  = lane >> 4;                   // 0..3
  const int frx = fr & 7;

  for (int k0 = 0; k0 < K; k0 += 64) {
    #pragma unroll
    for (int j = 0; j < 4; ++j) {
      const int r = wave * 32 + j * 8;
      gload_lds16(A  + (long)(bm + r + srow) * K + k0 + scol, &As[r][0]);
      gload_lds16(Bt + (long)(bn + r + srow) * K + k0 + scol, &Bs[r][0]);
    }
    __syncthreads();   // drains vmcnt -> LDS writes visible
    #pragma unroll
    for (int kk = 0; kk < 2; ++kk) {
      const int col = ((kk * 4 + g4) ^ frx) * 8;   // swizzled read col (shorts)
      bf16x8 af[4], bfr[4];
      #pragma unroll
      for (int m = 0; m < 4; ++m)
        af[m] = *(const bf16x8*)&As[wr * 64 + m * 16 + fr][col];
      #pragma unroll
      for (int n = 0; n < 4; ++n)
        bfr[n] = *(const bf16x8*)&Bs[wc * 64 + n * 16 + fr][col];
      #pragma unroll
      for (int m = 0; m < 4; ++m)
        #pragma unroll
        for (int n = 0; n < 4; ++n)
          acc[m][n] = __builtin_amdgcn_mfma_f32_16x16x32_bf16(af[m], bfr[n], acc[m][n], 0, 0, 0);
    }
    __syncthreads();
  }

  const int cr4 = (lane >> 4) * 4;
  const int cc  = lane & 15;
  #pragma unroll
  for (int m = 0; m < 4; ++m) {
    #pragma unroll
    for (int r = 0; r < 4; ++r) {
      int gm = bm + wr * 64 + m * 16 + cr4 + r;
      if (gm >= M) continue;
      #pragma unroll
      for (int n = 0; n < 4; ++n) {
        int gn = bn + wc * 64 + n * 16 + cc;
        float v = acc[m][n][r];
        if (HAS_BIAS) v += bias[gn];
        if (DO_RELU) v = fmaxf(v, 0.f);
        Cout[(long)gm * N + gn] = f2bf(v);
      }
    }
  }
}

// lin1 GEMM + scan_p1 riders (blocks [0, NSB))
__global__ __launch_bounds__(256) void gemm_lin1(
    const short* __restrict__ A, const short* __restrict__ Bt,
    const float* __restrict__ bias, short* __restrict__ Cout,
    const int* __restrict__ cnt, int* __restrict__ rowptr,
    int* __restrict__ bsum, float* __restrict__ dinv)
{
  if (blockIdx.x < NSB) { scan_p1_body(cnt, rowptr, bsum, dinv); return; }
  int gb = blockIdx.x - NSB;
  gemm_body<1, 1>(A, Bt, bias, Cout, NN, DIN, DH, gb & 3, gb >> 2);
}

// conv1 GEMM + scan_p3 riders (blocks [0, NSB))
__global__ __launch_bounds__(256) void gemm_conv1(
    const short* __restrict__ A, const short* __restrict__ Bt,
    short* __restrict__ Cout, int* __restrict__ rowptr,
    const int* __restrict__ bsum)
{
  if (blockIdx.x < NSB) { scan_p3_body(rowptr, bsum); return; }
  int gb = blockIdx.x - NSB;
  gemm_body<0, 0>(A, Bt, nullptr, Cout, NN, DH, DC, gb & 1, gb >> 1);
}

// conv2 GEMM (plain)
__global__ __launch_bounds__(256) void gemm_conv2(
    const short* __restrict__ A, const short* __restrict__ Bt,
    short* __restrict__ Cout)
{
  gemm_body<0, 0>(A, Bt, nullptr, Cout, NN, DC, DC, blockIdx.x & 1, blockIdx.x >> 1);
}

// ---------------- GCN aggregation v9: padded rows + 2-deep record pipeline ----
// 1 wave per node, 4 ch/lane (ushort4). Edge ranges are multiples of 8 (padded
// with zero-weight records), so the loop is uniform groups of 8. Records for
// group g+1 prefetch while group g's row gathers are in flight -> 1 memory
// round trip per group instead of 2. Output nt-stored.
__global__ __launch_bounds__(256) void aggregate_v9(
    const unsigned short* __restrict__ hw, const unsigned* __restrict__ ewp,
    const int* __restrict__ rowptr, const float* __restrict__ dinv,
    const float* __restrict__ bias, unsigned short* __restrict__ out)
{
  const int wid  = threadIdx.x >> 6;
  const int lane = threadIdx.x & 63;
  const int i = blockIdx.x * 4 + wid;
  if (i >= NN) return;
  const int c0 = lane * 4;
  const float di = dinv[i];

  ushort4 sv = *(const ushort4*)(hw + (long)i * DC + c0);
  const int s0 = rowptr[i], s1 = rowptr[i + 1];

  unsigned pkA[8];
  if (s0 < s1) {
    #pragma unroll
    for (int j = 0; j < 8; ++j) pkA[j] = __builtin_nontemporal_load(ewp + s0 + j);
  }

  const float dii = di * di;
  float acc0 = dii * bf2f(sv.x);
  float acc1 = dii * bf2f(sv.y);
  float acc2 = dii * bf2f(sv.z);
  float acc3 = dii * bf2f(sv.w);

  for (int e = s0; e < s1; e += 8) {
    ushort4 vv[8];
    #pragma unroll
    for (int j = 0; j < 8; ++j)
      vv[j] = *(const ushort4*)(hw + (long)(pkA[j] & 0xffffu) * DC + c0);
    unsigned pkB[8];
    if (e + 8 < s1) {            // wave-uniform branch (s0/s1 uniform per wave)
      #pragma unroll
      for (int j = 0; j < 8; ++j) pkB[j] = __builtin_nontemporal_load(ewp + e + 8 + j);
    } else {
      #pragma unroll
      for (int j = 0; j < 8; ++j) pkB[j] = 0u;
    }
    #pragma unroll
    for (int j = 0; j < 8; ++j) {
      float w = bf2f((unsigned short)(pkA[j] >> 16));
      acc0 += w * bf2f(vv[j].x);
      acc1 += w * bf2f(vv[j].y);
      acc2 += w * bf2f(vv[j].z);
      acc3 += w * bf2f(vv[j].w);
    }
    #pragma unroll
    for (int j = 0; j < 8; ++j) pkA[j] = pkB[j];
  }

  const float4 bv = *(const float4*)(bias + c0);
  ushort4 o;
  o.x = (unsigned short)f2bf(fmaxf(acc0 + bv.x, 0.f));
  o.y = (unsigned short)f2bf(fmaxf(acc1 + bv.y, 0.f));
  o.z = (unsigned short)f2bf(fmaxf(acc2 + bv.z, 0.f));
  o.w = (unsigned short)f2bf(fmaxf(acc3 + bv.w, 0.f));
  unsigned long long po = __builtin_bit_cast(unsigned long long, o);
  __builtin_nontemporal_store(po, (unsigned long long*)(out + (long)i * DC + c0));
}

// ---------------- pool + lin2 + lin3 fused v3 (bf16 input) ----------------
__global__ __launch_bounds__(256) void pool_mlp_v3(
    const unsigned short* __restrict__ h, const int* __restrict__ batch,
    const float* __restrict__ W2, const float* __restrict__ b2,
    const float* __restrict__ W3, const float* __restrict__ b3,
    float* __restrict__ out)
{
  __shared__ float part[4][DC];   // 4 KB
  __shared__ float gmean[DC];
  __shared__ float red[DL];
  const int g = blockIdx.x;
  const int t = threadIdx.x;
  const int wid = t >> 6;
  const int lane = t & 63;
  const int c0 = lane * 4;

  int lo = 0, hi = NN;
  while (lo < hi) { int mid = (lo + hi) >> 1; if (batch[mid] < g) lo = mid + 1; else hi = mid; }
  const int start = lo;
  hi = NN;
  while (lo < hi) { int mid = (lo + hi) >> 1; if (batch[mid] < g + 1) lo = mid + 1; else hi = mid; }
  const int end = lo;

  float4 a0 = {0.f, 0.f, 0.f, 0.f}, a1 = {0.f, 0.f, 0.f, 0.f};
  int i = start + wid;
  for (; i + 4 < end; i += 8) {
    ushort4 v0 = *(const ushort4*)(h + (long)i * DC + c0);
    ushort4 v1 = *(const ushort4*)(h + (long)(i + 4) * DC + c0);
    a0.x += bf2f(v0.x); a0.y += bf2f(v0.y); a0.z += bf2f(v0.z); a0.w += bf2f(v0.w);
    a1.x += bf2f(v1.x); a1.y += bf2f(v1.y); a1.z += bf2f(v1.z); a1.w += bf2f(v1.w);
  }
  if (i < end) {
    ushort4 v0 = *(const ushort4*)(h + (long)i * DC + c0);
    a0.x += bf2f(v0.x); a0.y += bf2f(v0.y); a0.z += bf2f(v0.z); a0.w += bf2f(v0.w);
  }
  a0.x += a1.x; a0.y += a1.y; a0.z += a1.z; a0.w += a1.w;
  *(float4*)&part[wid][c0] = a0;
  __syncthreads();
  if (wid == 0) {
    const float inv = 1.0f / fmaxf((float)(end - start), 1.f);
    float4 s0 = *(const float4*)&part[0][c0];
    float4 s1 = *(const float4*)&part[1][c0];
    float4 s2 = *(const float4*)&part[2][c0];
    float4 s3 = *(const float4*)&part[3][c0];
    float4 m;
    m.x = (s0.x + s1.x + s2.x + s3.x) * inv;
    m.y = (s0.y + s1.y + s2.y + s3.y) * inv;
    m.z = (s0.z + s1.z + s2.z + s3.z) * inv;
    m.w = (s0.w + s1.w + s2.w + s3.w) * inv;
    *(float4*)&gmean[c0] = m;
  }
  __syncthreads();
  if (t < DL) {
    float acc = b2[t];
    for (int k = 0; k < DC; ++k) acc = fmaf(gmean[k], W2[k * DL + t], acc);
    red[t] = fmaxf(acc, 0.f) * W3[t];
  }
  __syncthreads();
  for (int s2 = 64; s2 > 0; s2 >>= 1) {
    if (t < s2) red[t] += red[t + s2];
    __syncthreads();
  }
  if (t == 0) out[g] = red[0] + b3[0];
}

// ---------------- launch ----------------
extern "C" void kernel_launch(void* const* d_in, const int* in_sizes, int n_in,
                              void* d_out, int out_size, void* d_ws, size_t ws_size,
                              hipStream_t stream) {
  const float* x    = (const float*)d_in[0];
  const int*   ei   = (const int*)d_in[1];
  const int*   bat  = (const int*)d_in[2];
  const float* W1   = (const float*)d_in[3];
  const float* b1   = (const float*)d_in[4];
  const float* Wc1  = (const float*)d_in[5];
  const float* bc1  = (const float*)d_in[6];
  const float* Wc2  = (const float*)d_in[7];
  const float* bc2  = (const float*)d_in[8];
  const float* W2   = (const float*)d_in[9];
  const float* b2   = (const float*)d_in[10];
  const float* W3   = (const float*)d_in[11];
  const float* b3   = (const float*)d_in[12];
  float* out = (float*)d_out;

  char* ws = (char*)d_ws;
  short* xbf    = (short*)(ws + XBF_OFF);
  short* h1bf   = (short*)(ws + H1BF_OFF);
  unsigned short* hwbf = (unsigned short*)(ws + HWBF_OFF);
  unsigned short* h2bf = (unsigned short*)(ws + H2BF_OFF);
  unsigned short* h3bf = (unsigned short*)(ws + H3BF_OFF);
  short* W1t    = (short*)(ws + W1T_OFF);
  short* Wc1t   = (short*)(ws + WC1T_OFF);
  short* Wc2t   = (short*)(ws + WC2T_OFF);
  int*   cnt    = (int*)  (ws + CNT_OFF);
  int*   fill   = (int*)  (ws + FILL_OFF);
  unsigned* ewp = (unsigned*)(ws + EW_OFF);
  float* dinv   = (float*)(ws + DINV_OFF);
  int*   rowptr = (int*)  (ws + RP_OFF);
  int*   bsum   = (int*)  (ws + BSUM_OFF);

  const int* srcE = ei;
  const int* dstE = ei + NE;

  // zero cnt + fill + ewp (contiguous, 5.2MB) every call — padding slots must be 0
  hipMemsetAsync(cnt, 0, 5200000, stream);

  // prep0: degree count (blocks 0..3124) + x cvt + 3 weight transposes
  prep0<<<(NE + 1062144 + 255) / 256, 256, 0, stream>>>(
      srcE, dstE, cnt, x, xbf, W1, W1t, Wc1, Wc1t, Wc2, Wc2t);

  // lin1 GEMM (+ scan_p1 riders): h1 = relu(x @ W1 + b1) -> bf16
  gemm_lin1<<<NSB + 4 * 391, 256, 0, stream>>>(xbf, W1t, b1, h1bf,
                                               cnt, rowptr, bsum, dinv);
  // conv1 GEMM (+ scan_p3 riders): hw = h1 @ Wc1 -> bf16
  gemm_conv1<<<NSB + 2 * 391, 256, 0, stream>>>(h1bf, Wc1t, (short*)hwbf,
                                                rowptr, bsum);
  // CSR fill (needs completed rowptr)
  fill_csr<<<(NE + 255) / 256, 256, 0, stream>>>(srcE, dstE, rowptr, fill, dinv, ewp);

  // conv1 aggregate -> h2 (bias + relu) -> bf16
  aggregate_v9<<<(NN + 3) / 4, 256, 0, stream>>>(hwbf, ewp, rowptr, dinv, bc1, h2bf);
  // conv2 matmul: hw = h2 @ Wc2 -> bf16
  gemm_conv2<<<2 * 391, 256, 0, stream>>>((const short*)h2bf, Wc2t, (short*)hwbf);
  // conv2 aggregate -> h3 (bias + relu) -> bf16
  aggregate_v9<<<(NN + 3) / 4, 256, 0, stream>>>(hwbf, ewp, rowptr, dinv, bc2, h3bf);

  // pool + lin2 + lin3
  pool_mlp_v3<<<NG, 256, 0, stream>>>(h3bf, bat, W2, b2, W3, b3, out);
}

// Round 15
// 300.446 us; speedup vs baseline: 1.8692x; 1.0124x over previous
//
#include <hip/hip_runtime.h>
#include <hip/hip_bf16.h>

#define NN 50000
#define NE 800000
#define NG 256
#define DIN 128
#define DH 512
#define DC 256   // conv channels
#define DL 128   // lin2 out
#define NSB 196  // scan blocks: ceil(50000/256)

// ---------------- workspace layout (bytes) ----------------
#define XBF_OFF   0UL            // 50000*128*2  = 12,800,000
#define H1BF_OFF  12800000UL     // 50000*512*2  -> 64,000,000
#define HWBF_OFF  64000000UL     // 25,600,000 -> 89,600,000
#define H2BF_OFF  89600000UL     // 25,600,000 -> 115,200,000
#define H3BF_OFF  115200000UL    // 25,600,000 -> 140,800,000
#define W1T_OFF   140800000UL    // 131,072
#define WC1T_OFF  140931072UL    // 262,144
#define WC2T_OFF  141193216UL    // 131,072 -> 141,324,288
#define CNT_OFF   141324288UL    // 200,000
#define FILL_OFF  141524288UL    // 200,000
#define EW_OFF    141724288UL    // 1.2M records * 4B = 4,800,000 -> 146,524,288
                                  // (one memset covers CNT+FILL+EW = 5,200,000 B)
#define DINV_OFF  146524288UL    // 200,000
#define RP_OFF    146724288UL    // 200,004
#define BSUM_OFF  146924544UL    // 1024 (196 ints) -> end ~146.93 MB

using bf16x8 = __attribute__((ext_vector_type(8))) short;
using f32x4  = __attribute__((ext_vector_type(4))) float;

__device__ __forceinline__ short f2bf(float f) {
  unsigned u = __builtin_bit_cast(unsigned, f);
  unsigned r = u + 0x7fffu + ((u >> 16) & 1u);   // round-to-nearest-even
  return (short)(r >> 16);
}
__device__ __forceinline__ float bf2f(unsigned short u) {
  return __builtin_bit_cast(float, (unsigned)u << 16);
}

// async global->LDS, 16B per lane. LDS dest = wave-uniform base + lane*16.
__device__ __forceinline__ void gload_lds16(const void* g, void* l) {
  typedef const __attribute__((address_space(1))) unsigned gu32;
  typedef __attribute__((address_space(3))) unsigned lu32;
  __builtin_amdgcn_global_load_lds((gu32*)g, (lu32*)l, 16, 0, 0);
}

// ---------------- prep0: edge count + x->bf16 + 3 weight transposes (fused) ----
__global__ __launch_bounds__(256) void prep0(
    const int* __restrict__ src, const int* __restrict__ dst, int* __restrict__ cnt,
    const float* __restrict__ x, short* __restrict__ xbf,
    const float* __restrict__ W1, short* __restrict__ W1t,
    const float* __restrict__ Wc1, short* __restrict__ Wc1t,
    const float* __restrict__ Wc2, short* __restrict__ Wc2t) {
  long gidx = (long)blockIdx.x * 256 + threadIdx.x;
  if (gidx < NE) {                     // degree count
    atomicAdd(&cnt[dst[gidx]], 1);
    return;
  }
  long idx = gidx - NE;
  if (idx < 800000) {                  // x cvt, 8 elems/thread
    const float4* p = (const float4*)x + idx * 2;
    float4 a = p[0], b = p[1];
    bf16x8 o;
    o[0] = f2bf(a.x); o[1] = f2bf(a.y); o[2] = f2bf(a.z); o[3] = f2bf(a.w);
    o[4] = f2bf(b.x); o[5] = f2bf(b.y); o[6] = f2bf(b.z); o[7] = f2bf(b.w);
    *(bf16x8*)(xbf + idx * 8) = o;
  } else if (idx < 865536) {
    int j = (int)(idx - 800000);       // W1t[512][128]
    int n = j >> 7, k = j & 127;
    W1t[j] = f2bf(W1[k * DH + n]);
  } else if (idx < 996608) {
    int j = (int)(idx - 865536);       // Wc1t[256][512]
    int n = j >> 9, k = j & 511;
    Wc1t[j] = f2bf(Wc1[k * DC + n]);
  } else if (idx < 1062144) {
    int j = (int)(idx - 996608);       // Wc2t[256][256]
    int n = j >> 8, k = j & 255;
    Wc2t[j] = f2bf(Wc2[k * DC + n]);
  }
}

// ---------------- scan rider bodies (256-thread blocks) ----------------
// Scans PADDED degrees ceil(d/8)*8 so every node's edge range is a multiple of 8
// (padding slots are zero records: src=0, weight=+0.0 -> exact-zero contributions).
__device__ __forceinline__ void scan_p1_body(
    const int* __restrict__ cnt, int* __restrict__ rowptr,
    int* __restrict__ bsum, float* __restrict__ dinv) {
  __shared__ int wsum[4];
  const int b = blockIdx.x;
  const int idx = b * 256 + threadIdx.x;
  const int lane = threadIdx.x & 63, wid = threadIdx.x >> 6;
  int v  = (idx < NN) ? cnt[idx] : 0;
  int vp = (idx < NN) ? ((v + 7) & ~7) : 0;   // padded degree
  int incl = vp;
  #pragma unroll
  for (int s = 1; s < 64; s <<= 1) {
    int t = __shfl_up(incl, s, 64);
    if (lane >= s) incl += t;
  }
  if (lane == 63) wsum[wid] = incl;
  __syncthreads();
  int woff = 0;
  for (int w = 0; w < wid; ++w) woff += wsum[w];
  if (idx <= NN) rowptr[idx] = woff + incl - vp;   // idx==NN -> padded total prefix
  if (idx < NN)  dinv[idx] = 1.0f / sqrtf((float)(v + 1));   // +1 self-loop
  if (threadIdx.x == 255) bsum[b] = woff + incl;
}

__device__ __forceinline__ void scan_p3_body(
    int* __restrict__ rowptr, const int* __restrict__ bsum) {
  __shared__ int r4[4];
  const int b = blockIdx.x;
  const int t = threadIdx.x;
  const int lane = t & 63, wid = t >> 6;
  int v = (t < b) ? bsum[t] : 0;      // b <= 195 < 256; bsum has 196 entries
  #pragma unroll
  for (int s = 32; s > 0; s >>= 1) v += __shfl_down(v, s, 64);
  if (lane == 0) r4[wid] = v;
  __syncthreads();
  const int off = r4[0] + r4[1] + r4[2] + r4[3];
  const int idx = b * 256 + t;
  if (idx <= NN) rowptr[idx] += off;
}

// ---------------- fill CSR: packed 4B edge record = u16 src | bf16 weight ----
__global__ void fill_csr(const int* __restrict__ src, const int* __restrict__ dst,
                         const int* __restrict__ rowptr, int* __restrict__ fill,
                         const float* __restrict__ dinv, unsigned* __restrict__ ewp) {
  int e = blockIdx.x * blockDim.x + threadIdx.x;
  if (e < NE) {
    int d = dst[e];
    int s = src[e];
    int pos = rowptr[d] + atomicAdd(&fill[d], 1);
    float w = dinv[d] * dinv[s];
    ewp[pos] = (unsigned)s | ((unsigned)(unsigned short)f2bf(w) << 16);
  }
}

// ---------------- bf16 MFMA GEMM body: BK=64, swizzled LDS, LDS-repack epilogue --
// 128x128 tile, 4 waves (2x2), 16x16x32 MFMA, 4x4 fragments/wave.
// One 32KB LDS buffer: As(8192 shorts) + Bs(8192 shorts) during the K-loop,
// reused as the 128x128 bf16 C tile for the vectorized epilogue:
//   phase A: scalar b16 LDS writes (bias/relu/convert folded in)
//   phase B: ds_read_b128 + coalesced global_store_dwordx4 (1KB/wave-instr)
// vs the old 64 scalar 2-byte global stores per thread (store-bound).
template<int DO_RELU, int HAS_BIAS>
__device__ __forceinline__ void gemm_body(
    const short* __restrict__ A, const short* __restrict__ Bt,
    const float* __restrict__ bias, short* __restrict__ Cout,
    int M, int K, int N, int bxi, int byi)
{
  __shared__ __align__(16) short lds[16384];   // 32 KB
  short* Asb = lds;                            // [128][64]
  short* Bsb = lds + 8192;                     // [128][64]
  const int tid  = threadIdx.x;
  const int lane = tid & 63;
  const int wave = tid >> 6;
  const int wr   = wave >> 1;
  const int wc   = wave & 1;
  const int bm = byi * 128;
  const int bn = bxi * 128;

  const int srow = lane >> 3;                  // 0..7 within 8-row chunk
  const int scol = ((lane & 7) ^ srow) * 8;    // swizzled source col (shorts)

  f32x4 acc[4][4];
  #pragma unroll
  for (int m = 0; m < 4; ++m)
    #pragma unroll
    for (int n = 0; n < 4; ++n)
      acc[m][n] = f32x4{0.f, 0.f, 0.f, 0.f};

  const int fr  = lane & 15;
  const int g4  = lane >> 4;                   // 0..3
  const int frx = fr & 7;

  for (int k0 = 0; k0 < K; k0 += 64) {
    #pragma unroll
    for (int j = 0; j < 4; ++j) {
      const int r = wave * 32 + j * 8;
      gload_lds16(A  + (long)(bm + r + srow) * K + k0 + scol, &Asb[r * 64]);
      gload_lds16(Bt + (long)(bn + r + srow) * K + k0 + scol, &Bsb[r * 64]);
    }
    __syncthreads();   // drains vmcnt -> LDS writes visible
    #pragma unroll
    for (int kk = 0; kk < 2; ++kk) {
      const int col = ((kk * 4 + g4) ^ frx) * 8;   // swizzled read col (shorts)
      bf16x8 af[4], bfr[4];
      #pragma unroll
      for (int m = 0; m < 4; ++m)
        af[m] = *(const bf16x8*)&Asb[(wr * 64 + m * 16 + fr) * 64 + col];
      #pragma unroll
      for (int n = 0; n < 4; ++n)
        bfr[n] = *(const bf16x8*)&Bsb[(wc * 64 + n * 16 + fr) * 64 + col];
      #pragma unroll
      for (int m = 0; m < 4; ++m)
        #pragma unroll
        for (int n = 0; n < 4; ++n)
          acc[m][n] = __builtin_amdgcn_mfma_f32_16x16x32_bf16(af[m], bfr[n], acc[m][n], 0, 0, 0);
    }
    __syncthreads();
  }

  // ---- epilogue phase A: acc -> LDS C tile [128][128] bf16 (bias/relu folded) ----
  const int cr4 = (lane >> 4) * 4;
  const int cc  = lane & 15;
  #pragma unroll
  for (int m = 0; m < 4; ++m) {
    #pragma unroll
    for (int n = 0; n < 4; ++n) {
      const int colc = wc * 64 + n * 16 + cc;
      float b = HAS_BIAS ? bias[bn + colc] : 0.f;
      #pragma unroll
      for (int r = 0; r < 4; ++r) {
        int row = wr * 64 + m * 16 + cr4 + r;
        float v = acc[m][n][r];
        if (HAS_BIAS) v += b;
        if (DO_RELU) v = fmaxf(v, 0.f);
        lds[row * 128 + colc] = f2bf(v);
      }
    }
  }
  __syncthreads();
  // ---- epilogue phase B: LDS -> global, 16B/lane, 1KB coalesced per wave ----
  #pragma unroll
  for (int rd = 0; rd < 8; ++rd) {
    int off = rd * 2048 + tid * 8;     // shorts
    int row = off >> 7;
    int col = off & 127;
    int gm = bm + row;
    if (gm < M) {
      bf16x8 vv = *(const bf16x8*)&lds[off];
      *(bf16x8*)&Cout[(long)gm * N + bn + col] = vv;
    }
  }
}

// lin1 GEMM + scan_p1 riders (blocks [0, NSB))
__global__ __launch_bounds__(256) void gemm_lin1(
    const short* __restrict__ A, const short* __restrict__ Bt,
    const float* __restrict__ bias, short* __restrict__ Cout,
    const int* __restrict__ cnt, int* __restrict__ rowptr,
    int* __restrict__ bsum, float* __restrict__ dinv)
{
  if (blockIdx.x < NSB) { scan_p1_body(cnt, rowptr, bsum, dinv); return; }
  int gb = blockIdx.x - NSB;
  gemm_body<1, 1>(A, Bt, bias, Cout, NN, DIN, DH, gb & 3, gb >> 2);
}

// conv1 GEMM + scan_p3 riders (blocks [0, NSB))
__global__ __launch_bounds__(256) void gemm_conv1(
    const short* __restrict__ A, const short* __restrict__ Bt,
    short* __restrict__ Cout, int* __restrict__ rowptr,
    const int* __restrict__ bsum)
{
  if (blockIdx.x < NSB) { scan_p3_body(rowptr, bsum); return; }
  int gb = blockIdx.x - NSB;
  gemm_body<0, 0>(A, Bt, nullptr, Cout, NN, DH, DC, gb & 1, gb >> 1);
}

// conv2 GEMM (plain)
__global__ __launch_bounds__(256) void gemm_conv2(
    const short* __restrict__ A, const short* __restrict__ Bt,
    short* __restrict__ Cout)
{
  gemm_body<0, 0>(A, Bt, nullptr, Cout, NN, DC, DC, blockIdx.x & 1, blockIdx.x >> 1);
}

// ---------------- GCN aggregation v9: padded rows + 2-deep record pipeline ----
__global__ __launch_bounds__(256) void aggregate_v9(
    const unsigned short* __restrict__ hw, const unsigned* __restrict__ ewp,
    const int* __restrict__ rowptr, const float* __restrict__ dinv,
    const float* __restrict__ bias, unsigned short* __restrict__ out)
{
  const int wid  = threadIdx.x >> 6;
  const int lane = threadIdx.x & 63;
  const int i = blockIdx.x * 4 + wid;
  if (i >= NN) return;
  const int c0 = lane * 4;
  const float di = dinv[i];

  ushort4 sv = *(const ushort4*)(hw + (long)i * DC + c0);
  const int s0 = rowptr[i], s1 = rowptr[i + 1];

  unsigned pkA[8];
  if (s0 < s1) {
    #pragma unroll
    for (int j = 0; j < 8; ++j) pkA[j] = __builtin_nontemporal_load(ewp + s0 + j);
  }

  const float dii = di * di;
  float acc0 = dii * bf2f(sv.x);
  float acc1 = dii * bf2f(sv.y);
  float acc2 = dii * bf2f(sv.z);
  float acc3 = dii * bf2f(sv.w);

  for (int e = s0; e < s1; e += 8) {
    ushort4 vv[8];
    #pragma unroll
    for (int j = 0; j < 8; ++j)
      vv[j] = *(const ushort4*)(hw + (long)(pkA[j] & 0xffffu) * DC + c0);
    unsigned pkB[8];
    if (e + 8 < s1) {            // wave-uniform branch (s0/s1 uniform per wave)
      #pragma unroll
      for (int j = 0; j < 8; ++j) pkB[j] = __builtin_nontemporal_load(ewp + e + 8 + j);
    } else {
      #pragma unroll
      for (int j = 0; j < 8; ++j) pkB[j] = 0u;
    }
    #pragma unroll
    for (int j = 0; j < 8; ++j) {
      float w = bf2f((unsigned short)(pkA[j] >> 16));
      acc0 += w * bf2f(vv[j].x);
      acc1 += w * bf2f(vv[j].y);
      acc2 += w * bf2f(vv[j].z);
      acc3 += w * bf2f(vv[j].w);
    }
    #pragma unroll
    for (int j = 0; j < 8; ++j) pkA[j] = pkB[j];
  }

  const float4 bv = *(const float4*)(bias + c0);
  ushort4 o;
  o.x = (unsigned short)f2bf(fmaxf(acc0 + bv.x, 0.f));
  o.y = (unsigned short)f2bf(fmaxf(acc1 + bv.y, 0.f));
  o.z = (unsigned short)f2bf(fmaxf(acc2 + bv.z, 0.f));
  o.w = (unsigned short)f2bf(fmaxf(acc3 + bv.w, 0.f));
  unsigned long long po = __builtin_bit_cast(unsigned long long, o);
  __builtin_nontemporal_store(po, (unsigned long long*)(out + (long)i * DC + c0));
}

// ---------------- pool + lin2 + lin3 fused v3 (bf16 input) ----------------
__global__ __launch_bounds__(256) void pool_mlp_v3(
    const unsigned short* __restrict__ h, const int* __restrict__ batch,
    const float* __restrict__ W2, const float* __restrict__ b2,
    const float* __restrict__ W3, const float* __restrict__ b3,
    float* __restrict__ out)
{
  __shared__ float part[4][DC];   // 4 KB
  __shared__ float gmean[DC];
  __shared__ float red[DL];
  const int g = blockIdx.x;
  const int t = threadIdx.x;
  const int wid = t >> 6;
  const int lane = t & 63;
  const int c0 = lane * 4;

  int lo = 0, hi = NN;
  while (lo < hi) { int mid = (lo + hi) >> 1; if (batch[mid] < g) lo = mid + 1; else hi = mid; }
  const int start = lo;
  hi = NN;
  while (lo < hi) { int mid = (lo + hi) >> 1; if (batch[mid] < g + 1) lo = mid + 1; else hi = mid; }
  const int end = lo;

  float4 a0 = {0.f, 0.f, 0.f, 0.f}, a1 = {0.f, 0.f, 0.f, 0.f};
  int i = start + wid;
  for (; i + 4 < end; i += 8) {
    ushort4 v0 = *(const ushort4*)(h + (long)i * DC + c0);
    ushort4 v1 = *(const ushort4*)(h + (long)(i + 4) * DC + c0);
    a0.x += bf2f(v0.x); a0.y += bf2f(v0.y); a0.z += bf2f(v0.z); a0.w += bf2f(v0.w);
    a1.x += bf2f(v1.x); a1.y += bf2f(v1.y); a1.z += bf2f(v1.z); a1.w += bf2f(v1.w);
  }
  if (i < end) {
    ushort4 v0 = *(const ushort4*)(h + (long)i * DC + c0);
    a0.x += bf2f(v0.x); a0.y += bf2f(v0.y); a0.z += bf2f(v0.z); a0.w += bf2f(v0.w);
  }
  a0.x += a1.x; a0.y += a1.y; a0.z += a1.z; a0.w += a1.w;
  *(float4*)&part[wid][c0] = a0;
  __syncthreads();
  if (wid == 0) {
    const float inv = 1.0f / fmaxf((float)(end - start), 1.f);
    float4 s0 = *(const float4*)&part[0][c0];
    float4 s1 = *(const float4*)&part[1][c0];
    float4 s2 = *(const float4*)&part[2][c0];
    float4 s3 = *(const float4*)&part[3][c0];
    float4 m;
    m.x = (s0.x + s1.x + s2.x + s3.x) * inv;
    m.y = (s0.y + s1.y + s2.y + s3.y) * inv;
    m.z = (s0.z + s1.z + s2.z + s3.z) * inv;
    m.w = (s0.w + s1.w + s2.w + s3.w) * inv;
    *(float4*)&gmean[c0] = m;
  }
  __syncthreads();
  if (t < DL) {
    float acc = b2[t];
    for (int k = 0; k < DC; ++k) acc = fmaf(gmean[k], W2[k * DL + t], acc);
    red[t] = fmaxf(acc, 0.f) * W3[t];
  }
  __syncthreads();
  for (int s2 = 64; s2 > 0; s2 >>= 1) {
    if (t < s2) red[t] += red[t + s2];
    __syncthreads();
  }
  if (t == 0) out[g] = red[0] + b3[0];
}

// ---------------- launch ----------------
extern "C" void kernel_launch(void* const* d_in, const int* in_sizes, int n_in,
                              void* d_out, int out_size, void* d_ws, size_t ws_size,
                              hipStream_t stream) {
  const float* x    = (const float*)d_in[0];
  const int*   ei   = (const int*)d_in[1];
  const int*   bat  = (const int*)d_in[2];
  const float* W1   = (const float*)d_in[3];
  const float* b1   = (const float*)d_in[4];
  const float* Wc1  = (const float*)d_in[5];
  const float* bc1  = (const float*)d_in[6];
  const float* Wc2  = (const float*)d_in[7];
  const float* bc2  = (const float*)d_in[8];
  const float* W2   = (const float*)d_in[9];
  const float* b2   = (const float*)d_in[10];
  const float* W3   = (const float*)d_in[11];
  const float* b3   = (const float*)d_in[12];
  float* out = (float*)d_out;

  char* ws = (char*)d_ws;
  short* xbf    = (short*)(ws + XBF_OFF);
  short* h1bf   = (short*)(ws + H1BF_OFF);
  unsigned short* hwbf = (unsigned short*)(ws + HWBF_OFF);
  unsigned short* h2bf = (unsigned short*)(ws + H2BF_OFF);
  unsigned short* h3bf = (unsigned short*)(ws + H3BF_OFF);
  short* W1t    = (short*)(ws + W1T_OFF);
  short* Wc1t   = (short*)(ws + WC1T_OFF);
  short* Wc2t   = (short*)(ws + WC2T_OFF);
  int*   cnt    = (int*)  (ws + CNT_OFF);
  int*   fill   = (int*)  (ws + FILL_OFF);
  unsigned* ewp = (unsigned*)(ws + EW_OFF);
  float* dinv   = (float*)(ws + DINV_OFF);
  int*   rowptr = (int*)  (ws + RP_OFF);
  int*   bsum   = (int*)  (ws + BSUM_OFF);

  const int* srcE = ei;
  const int* dstE = ei + NE;

  // zero cnt + fill + ewp (contiguous, 5.2MB) every call — padding slots must be 0
  hipMemsetAsync(cnt, 0, 5200000, stream);

  // prep0: degree count (blocks 0..3124) + x cvt + 3 weight transposes
  prep0<<<(NE + 1062144 + 255) / 256, 256, 0, stream>>>(
      srcE, dstE, cnt, x, xbf, W1, W1t, Wc1, Wc1t, Wc2, Wc2t);

  // lin1 GEMM (+ scan_p1 riders): h1 = relu(x @ W1 + b1) -> bf16
  gemm_lin1<<<NSB + 4 * 391, 256, 0, stream>>>(xbf, W1t, b1, h1bf,
                                               cnt, rowptr, bsum, dinv);
  // conv1 GEMM (+ scan_p3 riders): hw = h1 @ Wc1 -> bf16
  gemm_conv1<<<NSB + 2 * 391, 256, 0, stream>>>(h1bf, Wc1t, (short*)hwbf,
                                                rowptr, bsum);
  // CSR fill (needs completed rowptr)
  fill_csr<<<(NE + 255) / 256, 256, 0, stream>>>(srcE, dstE, rowptr, fill, dinv, ewp);

  // conv1 aggregate -> h2 (bias + relu) -> bf16
  aggregate_v9<<<(NN + 3) / 4, 256, 0, stream>>>(hwbf, ewp, rowptr, dinv, bc1, h2bf);
  // conv2 matmul: hw = h2 @ Wc2 -> bf16
  gemm_conv2<<<2 * 391, 256, 0, stream>>>((const short*)h2bf, Wc2t, (short*)hwbf);
  // conv2 aggregate -> h3 (bias + relu) -> bf16
  aggregate_v9<<<(NN + 3) / 4, 256, 0, stream>>>(hwbf, ewp, rowptr, dinv, bc2, h3bf);

  // pool + lin2 + lin3
  pool_mlp_v3<<<NG, 256, 0, stream>>>(h3bf, bat, W2, b2, W3, b3, out);
}